// Round 9
// baseline (421.674 us; speedup 1.0000x reference)
//
#include <hip/hip_runtime.h>
#include <cstddef>

#define B 128
#define R 1024

typedef __attribute__((ext_vector_type(8))) short short8;
typedef __attribute__((ext_vector_type(4))) float f32x4;

__device__ __forceinline__ float sigf(float x) { return 1.0f / (1.0f + __expf(-x)); }

__device__ __forceinline__ short f2bf(float f) {
    unsigned int u = __float_as_uint(f);
    u += 0x7fff + ((u >> 16) & 1);   // RNE
    return (short)(u >> 16);
}

__device__ __forceinline__ short8 cvt8(float4 u, float4 v) {
    short8 r;
    r[0] = f2bf(u.x); r[1] = f2bf(u.y); r[2] = f2bf(u.z); r[3] = f2bf(u.w);
    r[4] = f2bf(v.x); r[5] = f2bf(v.y); r[6] = f2bf(v.z); r[7] = f2bf(v.w);
    return r;
}

// ---------------------------------------------------------------------------
// Split-K multi-job bf16-MFMA GEMM. M=128, BN=64, BK=32, 4 waves (each 32x64).
// C[m,n] += sum_k A[m,k]*W[n,k]  via atomicAdd (C pre-zeroed; bias in epilogue).
// ---------------------------------------------------------------------------
struct GJob {
    const float* A1; const float* A2; const float* A3;
    const float* W1; const float* W2; const float* W3;
    float* C;
    int lda1, lda2, lda3;
    int ldw1, ldw2, ldw3;
    int K1, K12, Ktot;
    int ldc, Kchunk, nb;
};

__global__ __launch_bounds__(256) void gemm_sk_kernel(GJob j0, GJob j1, GJob j2, int njobs)
{
    GJob j = j0;
    int nbx = blockIdx.x;
    if (njobs > 1 && nbx >= j.nb) { nbx -= j.nb; j = j1; }
    if (njobs > 2 && nbx >= j.nb) { nbx -= j.nb; j = j2; }

    const int bn   = nbx * 64;
    const int kbeg = blockIdx.y * j.Kchunk;
    const int kend = kbeg + j.Kchunk;

    __shared__ short sA[128 * 40];
    __shared__ short sB[64 * 40];
    const int tid  = threadIdx.x;
    const int rA   = tid >> 1;
    const int kha  = (tid & 1) << 4;
    const int rB   = tid >> 2;
    const int khb  = (tid & 3) << 3;
    const int lane = tid & 63;
    const int wid  = tid >> 6;
    const int wm   = wid * 32;
    const int fr_  = lane & 15;
    const int kof  = (lane >> 4) * 8;

    f32x4 acc[2][4];
#pragma unroll
    for (int m = 0; m < 2; ++m)
#pragma unroll
        for (int n = 0; n < 4; ++n)
            acc[m][n] = (f32x4)0.0f;

    for (int k0 = kbeg; k0 < kend; k0 += 32) {
        int kgA = k0 + kha;
        const float* pa;
        if (kgA < j.K1)       pa = j.A1 + (size_t)rA * j.lda1 + kgA;
        else if (kgA < j.K12) pa = j.A2 + (size_t)rA * j.lda2 + (kgA - j.K1);
        else                  pa = j.A3 + (size_t)rA * j.lda3 + (kgA - j.K12);
        int kgB = k0 + khb;
        const float* pw;
        if (kgB < j.K1)       pw = j.W1 + (size_t)(bn + rB) * j.ldw1 + kgB;
        else if (kgB < j.K12) pw = j.W2 + (size_t)(bn + rB) * j.ldw2 + (kgB - j.K1);
        else                  pw = j.W3 + (size_t)(bn + rB) * j.ldw3 + (kgB - j.K12);

        float4 a0 = ((const float4*)pa)[0];
        float4 a1 = ((const float4*)pa)[1];
        float4 a2 = ((const float4*)pa)[2];
        float4 a3 = ((const float4*)pa)[3];
        float4 w0 = ((const float4*)pw)[0];
        float4 w1 = ((const float4*)pw)[1];
        __syncthreads();
        *(short8*)&sA[rA * 40 + kha]     = cvt8(a0, a1);
        *(short8*)&sA[rA * 40 + kha + 8] = cvt8(a2, a3);
        *(short8*)&sB[rB * 40 + khb]     = cvt8(w0, w1);
        __syncthreads();
        short8 af[2], bf[4];
#pragma unroll
        for (int m = 0; m < 2; ++m)
            af[m] = *(const short8*)&sA[(wm + m * 16 + fr_) * 40 + kof];
#pragma unroll
        for (int n = 0; n < 4; ++n)
            bf[n] = *(const short8*)&sB[(n * 16 + fr_) * 40 + kof];
#pragma unroll
        for (int m = 0; m < 2; ++m)
#pragma unroll
            for (int n = 0; n < 4; ++n)
                acc[m][n] = __builtin_amdgcn_mfma_f32_16x16x32_bf16(af[m], bf[n], acc[m][n], 0, 0, 0);
    }

#pragma unroll
    for (int m = 0; m < 2; ++m) {
        int row0 = wm + m * 16 + ((lane >> 4) << 2);
#pragma unroll
        for (int n = 0; n < 4; ++n) {
            int col = bn + n * 16 + fr_;
#pragma unroll
            for (int rg = 0; rg < 4; ++rg)
                atomicAdd(&j.C[(size_t)(row0 + rg) * j.ldc + col], acc[m][n][rg]);
        }
    }
}

// ---------------------------------------------------------------------------
// Fused prologue. Blocks:
//  [0,ZB): zero atomic ws + init out bias
//  [ZB,ZB+384): concat3 -> att_in
//  [ZB+384, +6272): P -> Pbf in FRAGMENT order (wave per (rt,ks))
//  [ZB+6656, +256): cfe_w -> Wbf in fragment order
// ---------------------------------------------------------------------------
__global__ __launch_bounds__(256) void prologue_kernel(
    float* __restrict__ ws, int nws, float* __restrict__ o, const float* __restrict__ bias,
    const float* __restrict__ ph, const float* __restrict__ fc, const float* __restrict__ xt,
    float* __restrict__ att_in,
    const float* __restrict__ P, const float* __restrict__ W,
    short* __restrict__ Pbf, short* __restrict__ Wbf, int ZB)
{
    int blk = blockIdx.x;
    int tid = threadIdx.x;
    if (blk < ZB) {
        int idx = blk * 256 + tid;
        if (idx < nws) ws[idx] = 0.0f;
        else if (idx < nws + 131072) { int i = idx - nws; o[i] = bias[i & 1023]; }
        return;
    }
    blk -= ZB;
    if (blk < 384) {
        int idx = blk * 256 + tid;
        int r = idx / 768, c4 = idx - r * 768;
        int col = c4 * 4;
        const float* src = (col < 1024) ? (ph + (size_t)r * 1024 + col)
                         : (col < 2048) ? (fc + (size_t)r * 1024 + col - 1024)
                                        : (xt + (size_t)r * 1024 + col - 2048);
        *(float4*)(att_in + (size_t)r * 3072 + col) = *(const float4*)src;
        return;
    }
    blk -= 384;
    int lane = tid & 63;
    int fr = lane & 15, kg = lane >> 4;
    if (blk < 6272) {
        int w = blk * 4 + (tid >> 6);     // 0..25087 = rt*16+ks
        int rt = w >> 4, ks = w & 15;
        const float* src = P + (size_t)(rt * 16 + fr) * 512 + ks * 32 + kg * 8;
        float4 u = ((const float4*)src)[0];
        float4 v = ((const float4*)src)[1];
        *(short8*)(Pbf + ((size_t)w * 64 + lane) * 8) = cvt8(u, v);
    } else {
        int w = (blk - 6272) * 4 + (tid >> 6);   // 0..1023 = ct*16+ks
        int ct = w >> 4, ks = w & 15;
        const float* src = W + (size_t)(ct * 16 + fr) * 512 + ks * 32 + kg * 8;
        float4 u = ((const float4*)src)[0];
        float4 v = ((const float4*)src)[1];
        *(short8*)(Wbf + ((size_t)w * 64 + lane) * 8) = cvt8(u, v);
    }
}

// ---------------------------------------------------------------------------
// cfe v6: LDS-free, depth-3 software pipeline. Fragment-ordered Pbf/Wbf;
// each fragment = one coalesced 1KB load/wave, issued 2 iterations ahead
// (~260 wave-cycles > L2 latency). setprio(1) around MFMA cluster (T5).
// ---------------------------------------------------------------------------
__global__ __launch_bounds__(256, 2) void cfe_v6_kernel(
    const short* __restrict__ Pbf, const short* __restrict__ Wbf,
    const float* __restrict__ cb, const float* __restrict__ hoe,
    const float* __restrict__ ho_b, const float* __restrict__ aw,
    float* __restrict__ e)
{
    int p = blockIdx.x;
    int x8 = p & 7, rest = p >> 3;
    int n8 = rest & 7, q = rest >> 3;
    int m = q * 8 + x8;
    if (m >= 196) return;
    const int bm = m * 128, bn = n8 * 128;

    const int tid  = threadIdx.x;
    const int lane = tid & 63;
    const int wid  = tid >> 6;
    const int wm   = (wid >> 1) * 64;
    const int wn   = (wid & 1) * 64;
    const int fr_  = lane & 15;

    const short* pA = Pbf + (size_t)(bm + wm) * 512 + lane * 8;
    const short* pB = Wbf + (size_t)(bn + wn) * 512 + lane * 8;

    f32x4 acc[4][4];
#pragma unroll
    for (int mi = 0; mi < 4; ++mi)
#pragma unroll
        for (int n = 0; n < 4; ++n)
            acc[mi][n] = (f32x4)0.0f;

    short8 a[3][4], b[3][4];
#pragma unroll
    for (int mi = 0; mi < 4; ++mi) {
        a[0][mi] = *(const short8*)(pA + (mi * 16 + 0) * 512);
        b[0][mi] = *(const short8*)(pB + (mi * 16 + 0) * 512);
        a[1][mi] = *(const short8*)(pA + (mi * 16 + 1) * 512);
        b[1][mi] = *(const short8*)(pB + (mi * 16 + 1) * 512);
    }
#pragma unroll
    for (int ks = 0; ks < 16; ++ks) {
        const int cur = ks % 3, nx2 = (ks + 2) % 3;
        if (ks < 14) {
#pragma unroll
            for (int mi = 0; mi < 4; ++mi) {
                a[nx2][mi] = *(const short8*)(pA + (mi * 16 + ks + 2) * 512);
                b[nx2][mi] = *(const short8*)(pB + (mi * 16 + ks + 2) * 512);
            }
        }
        __builtin_amdgcn_s_setprio(1);
#pragma unroll
        for (int mi = 0; mi < 4; ++mi)
#pragma unroll
            for (int n = 0; n < 4; ++n)
                acc[mi][n] = __builtin_amdgcn_mfma_f32_16x16x32_bf16(a[cur][mi], b[cur][n], acc[mi][n], 0, 0, 0);
        __builtin_amdgcn_s_setprio(0);
    }

    // epilogue: per-row tanh-dot, shfl reduce over 16 lanes, atomic add
    const int l4 = lane >> 4;
    const int rbase = bm + wm + (l4 << 2);
    const int b0 = rbase / 196;
    const int b1 = (rbase + 51) / 196;
    float cba[4], awa[4], hv0[4], hv1[4];
#pragma unroll
    for (int n = 0; n < 4; ++n) {
        int col = bn + wn + n * 16 + fr_;
        cba[n] = cb[col] + ho_b[col];
        awa[n] = aw[col];
        hv0[n] = hoe[(size_t)b0 * R + col];
        hv1[n] = hoe[(size_t)b1 * R + col];
    }
#pragma unroll
    for (int mi = 0; mi < 4; ++mi) {
#pragma unroll
        for (int rg = 0; rg < 4; ++rg) {
            int gr = rbase + mi * 16 + rg;
            int bb = gr / 196;
            bool second = (bb != b0);
            float part = 0.0f;
#pragma unroll
            for (int n = 0; n < 4; ++n) {
                float hv = second ? hv1[n] : hv0[n];
                part += tanhf(acc[mi][n][rg] + cba[n] + hv) * awa[n];
            }
            part += __shfl_xor(part, 1);
            part += __shfl_xor(part, 2);
            part += __shfl_xor(part, 4);
            part += __shfl_xor(part, 8);
            if (fr_ == 0)
                atomicAdd(&e[bb * 197 + 1 + (gr - bb * 196)], part);
        }
    }
}

// fallback (ws too small for Pbf): fp32 inputs + in-kernel cvt, LDS staged
__global__ __launch_bounds__(256) void cfe_fallback_kernel(
    const float* __restrict__ P, const float* __restrict__ Wf,
    const float* __restrict__ cb, const float* __restrict__ hoe,
    const float* __restrict__ ho_b, const float* __restrict__ aw,
    float* __restrict__ e)
{
    int p = blockIdx.x;
    int x8 = p & 7, rest = p >> 3;
    int n8 = rest & 7, q = rest >> 3;
    int m = q * 8 + x8;
    if (m >= 196) return;
    const int bm = m * 128, bn = n8 * 128;

    __shared__ short sA[128 * 72];
    __shared__ short sB[128 * 72];
    const int tid  = threadIdx.x;
    const int lane = tid & 63;
    const int wid  = tid >> 6;
    const int wm   = (wid >> 1) * 64;
    const int wn   = (wid & 1) * 64;
    const int fr_  = lane & 15;
    const int kof  = (lane >> 4) * 8;

    f32x4 acc[4][4];
#pragma unroll
    for (int mi = 0; mi < 4; ++mi)
#pragma unroll
        for (int n = 0; n < 4; ++n)
            acc[mi][n] = (f32x4)0.0f;

    for (int k0 = 0; k0 < 512; k0 += 64) {
        __syncthreads();
        int row = tid >> 1;
        int half = (tid & 1) * 32;
        const float* pa = P + (size_t)(bm + row) * 512 + k0 + half;
        const float* pw = Wf + (size_t)(bn + row) * 512 + k0 + half;
#pragma unroll
        for (int c = 0; c < 32; c += 8) {
            float4 u = *(const float4*)(pa + c);
            float4 v = *(const float4*)(pa + c + 4);
            *(short8*)&sA[row * 72 + half + c] = cvt8(u, v);
            float4 uw = *(const float4*)(pw + c);
            float4 vw = *(const float4*)(pw + c + 4);
            *(short8*)&sB[row * 72 + half + c] = cvt8(uw, vw);
        }
        __syncthreads();
#pragma unroll
        for (int ks = 0; ks < 64; ks += 32) {
            short8 af[4], bf[4];
#pragma unroll
            for (int mi = 0; mi < 4; ++mi)
                af[mi] = *(const short8*)&sA[(wm + mi * 16 + fr_) * 72 + ks + kof];
#pragma unroll
            for (int n = 0; n < 4; ++n)
                bf[n] = *(const short8*)&sB[(wn + n * 16 + fr_) * 72 + ks + kof];
#pragma unroll
            for (int mi = 0; mi < 4; ++mi)
#pragma unroll
                for (int n = 0; n < 4; ++n)
                    acc[mi][n] = __builtin_amdgcn_mfma_f32_16x16x32_bf16(af[mi], bf[n], acc[mi][n], 0, 0, 0);
        }
    }

    const int l4 = lane >> 4;
    const int rbase = bm + wm + (l4 << 2);
    const int b0 = rbase / 196;
    const int b1 = (rbase + 51) / 196;
    float cba[4], awa[4], hv0[4], hv1[4];
#pragma unroll
    for (int n = 0; n < 4; ++n) {
        int col = bn + wn + n * 16 + fr_;
        cba[n] = cb[col] + ho_b[col];
        awa[n] = aw[col];
        hv0[n] = hoe[(size_t)b0 * R + col];
        hv1[n] = hoe[(size_t)b1 * R + col];
    }
#pragma unroll
    for (int mi = 0; mi < 4; ++mi) {
#pragma unroll
        for (int rg = 0; rg < 4; ++rg) {
            int gr = rbase + mi * 16 + rg;
            int bb = gr / 196;
            bool second = (bb != b0);
            float part = 0.0f;
#pragma unroll
            for (int n = 0; n < 4; ++n) {
                float hv = second ? hv1[n] : hv0[n];
                part += tanhf(acc[mi][n][rg] + cba[n] + hv) * awa[n];
            }
            part += __shfl_xor(part, 1);
            part += __shfl_xor(part, 2);
            part += __shfl_xor(part, 4);
            part += __shfl_xor(part, 8);
            if (fr_ == 0)
                atomicAdd(&e[bb * 197 + 1 + (gr - bb * 196)], part);
        }
    }
}

// vectorized LSTM epilogue (+ optional st fusion); self-zero g.
__global__ __launch_bounds__(256) void lstm_kernel(
    float* __restrict__ g, const float* __restrict__ bih, const float* __restrict__ bhh,
    const float* __restrict__ cprev, float* __restrict__ h, float* __restrict__ c,
    const float* __restrict__ n5, const float* __restrict__ nb1,
    const float* __restrict__ nb2, float* __restrict__ st)
{
    int t = blockIdx.x * 256 + threadIdx.x;   // 0..32767
    int b = t >> 8, d4 = (t & 255) * 4;
    float* gr = g + (size_t)b * 4096;
    float4 gi = *(float4*)(gr + d4);
    float4 gf = *(float4*)(gr + 1024 + d4);
    float4 gg = *(float4*)(gr + 2048 + d4);
    float4 go = *(float4*)(gr + 3072 + d4);
    float4 bi1 = *(const float4*)(bih + d4),        bh1 = *(const float4*)(bhh + d4);
    float4 bi2 = *(const float4*)(bih + 1024 + d4), bh2 = *(const float4*)(bhh + 1024 + d4);
    float4 bi3 = *(const float4*)(bih + 2048 + d4), bh3 = *(const float4*)(bhh + 2048 + d4);
    float4 bi4 = *(const float4*)(bih + 3072 + d4), bh4 = *(const float4*)(bhh + 3072 + d4);
    float4 cp = *(const float4*)(cprev + (size_t)b * 1024 + d4);
    float4 zero = {0.f, 0.f, 0.f, 0.f};
    *(float4*)(gr + d4) = zero; *(float4*)(gr + 1024 + d4) = zero;
    *(float4*)(gr + 2048 + d4) = zero; *(float4*)(gr + 3072 + d4) = zero;
    float4 cc, hh;
    float iv, fv, gv, ov, c2, tc;
    iv = sigf(gi.x + bi1.x + bh1.x); fv = sigf(gf.x + bi2.x + bh2.x);
    gv = tanhf(gg.x + bi3.x + bh3.x); ov = sigf(go.x + bi4.x + bh4.x);
    c2 = fv * cp.x + iv * gv; tc = tanhf(c2); cc.x = c2; hh.x = ov * tc;
    float tcx = tc;
    iv = sigf(gi.y + bi1.y + bh1.y); fv = sigf(gf.y + bi2.y + bh2.y);
    gv = tanhf(gg.y + bi3.y + bh3.y); ov = sigf(go.y + bi4.y + bh4.y);
    c2 = fv * cp.y + iv * gv; tc = tanhf(c2); cc.y = c2; hh.y = ov * tc;
    float tcy = tc;
    iv = sigf(gi.z + bi1.z + bh1.z); fv = sigf(gf.z + bi2.z + bh2.z);
    gv = tanhf(gg.z + bi3.z + bh3.z); ov = sigf(go.z + bi4.z + bh4.z);
    c2 = fv * cp.z + iv * gv; tc = tanhf(c2); cc.z = c2; hh.z = ov * tc;
    float tcz = tc;
    iv = sigf(gi.w + bi1.w + bh1.w); fv = sigf(gf.w + bi2.w + bh2.w);
    gv = tanhf(gg.w + bi3.w + bh3.w); ov = sigf(go.w + bi4.w + bh4.w);
    c2 = fv * cp.w + iv * gv; tc = tanhf(c2); cc.w = c2; hh.w = ov * tc;
    float tcw = tc;
    *(float4*)(c + (size_t)b * 1024 + d4) = cc;
    *(float4*)(h + (size_t)b * 1024 + d4) = hh;
    if (st) {
        float4 nv = *(const float4*)(n5 + (size_t)b * 1024 + d4);
        float4 n1 = *(const float4*)(nb1 + d4), n2 = *(const float4*)(nb2 + d4);
        float4 sv;
        sv.x = sigf(nv.x + n1.x + n2.x) * tcx;
        sv.y = sigf(nv.y + n1.y + n2.y) * tcy;
        sv.z = sigf(nv.z + n1.z + n2.z) * tcz;
        sv.w = sigf(nv.w + n1.w + n2.w) * tcw;
        *(float4*)(st + (size_t)b * 1024 + d4) = sv;
    }
}

// h_att epilogue: lang_in[:,0:1024] += biases (in place) and copy to h_att_out
__global__ __launch_bounds__(256) void hatt_epi_kernel(
    float* __restrict__ lang_in, const float* __restrict__ b1,
    const float* __restrict__ b2, float* __restrict__ h_att_out)
{
    int t = blockIdx.x * 256 + threadIdx.x;   // 0..32767
    int r = t >> 8, c4 = (t & 255) * 4;
    float4 v = *(float4*)(lang_in + (size_t)r * 4096 + c4);
    float4 x1 = *(const float4*)(b1 + c4), x2 = *(const float4*)(b2 + c4);
    v.x += x1.x + x2.x; v.y += x1.y + x2.y; v.z += x1.z + x2.z; v.w += x1.w + x2.w;
    *(float4*)(lang_in + (size_t)r * 4096 + c4) = v;
    *(float4*)(h_att_out + (size_t)r * 1024 + c4) = v;
}

// fused 3-module e (float4, coalesced): e[item] = sum_a tanh(p + ah + b2) * aw
__global__ __launch_bounds__(256) void att_e3_kernel(
    const float* __restrict__ p0, const float* __restrict__ p1, const float* __restrict__ p2,
    const float* __restrict__ ah3,
    const float* __restrict__ b0, const float* __restrict__ b1, const float* __restrict__ b2,
    const float* __restrict__ aw0, const float* __restrict__ aw1, const float* __restrict__ aw2,
    float* __restrict__ e3)
{
    int wid = threadIdx.x >> 6, lane = threadIdx.x & 63;
    int idx = blockIdx.x * 4 + wid;
    const float* p; const float* bb; const float* aw; int S, loc, mod;
    if (idx < 25088)      { mod = 0; loc = idx;          p = p0; bb = b0; aw = aw0; S = 196; }
    else if (idx < 50176) { mod = 1; loc = idx - 25088;  p = p1; bb = b1; aw = aw1; S = 196; }
    else                  { mod = 2; loc = idx - 50176;  p = p2; bb = b2; aw = aw2; S = 64; }
    int b = loc / S;
    const float4* pr = (const float4*)(p + (size_t)loc * 512);
    const float4* ab = (const float4*)(ah3 + (size_t)mod * 65536 + (size_t)b * 512);
    const float4* bb4 = (const float4*)bb;
    const float4* aw4 = (const float4*)aw;
    float sum = 0.0f;
#pragma unroll
    for (int k = 0; k < 2; ++k) {
        int a = k * 64 + lane;
        float4 pv = pr[a], av = ab[a], bv = bb4[a], wv = aw4[a];
        sum += tanhf(pv.x + av.x + bv.x) * wv.x;
        sum += tanhf(pv.y + av.y + bv.y) * wv.y;
        sum += tanhf(pv.z + av.z + bv.z) * wv.z;
        sum += tanhf(pv.w + av.w + bv.w) * wv.w;
    }
#pragma unroll
    for (int off = 32; off; off >>= 1) sum += __shfl_down(sum, off);
    if (lane == 0) e3[idx] = sum;
}

// fused 3-module softmax (mask + renorm), in place on e3
__global__ __launch_bounds__(256) void softmax3_kernel(
    float* __restrict__ e3, const float* __restrict__ am, const float* __restrict__ rm)
{
    __shared__ float red[256];
    int mod = blockIdx.x >> 7, b = blockIdx.x & 127, tid = threadIdx.x;
    int S = (mod == 2) ? 64 : 196;
    float* e = e3 + ((mod == 0) ? 0 : (mod == 1) ? 25088 : 50176) + (size_t)b * S;
    const float* mask = ((mod == 2) ? rm : am) + (size_t)b * S;
    float v = (tid < S) ? e[tid] : -3.4e38f;
    red[tid] = v; __syncthreads();
    for (int s = 128; s; s >>= 1) { if (tid < s) red[tid] = fmaxf(red[tid], red[tid + s]); __syncthreads(); }
    float m = red[0]; __syncthreads();
    float p = (tid < S) ? __expf(v - m) : 0.0f;
    red[tid] = p; __syncthreads();
    for (int s = 128; s; s >>= 1) { if (tid < s) red[tid] += red[tid + s]; __syncthreads(); }
    float s1 = red[0]; __syncthreads();
    float w = (tid < S) ? (p / s1) * mask[tid] : 0.0f;
    red[tid] = w; __syncthreads();
    for (int s = 128; s; s >>= 1) { if (tid < s) red[tid] += red[tid + s]; __syncthreads(); }
    float s2 = red[0];
    if (tid < S) e[tid] = w / s2;
}

// fused 3-module weighted sum, s-split x8, atomic into lang_in (zeroed)
__global__ __launch_bounds__(256) void wsum3_kernel(
    const float* __restrict__ e3,
    const float* __restrict__ f0, const float* __restrict__ f1, const float* __restrict__ f2,
    float* __restrict__ lang_in)
{
    int mod = blockIdx.x >> 7;
    int idx = (blockIdx.x & 127) * 256 + threadIdx.x;
    int b = idx >> 8, d4 = idx & 255;
    int S = (mod == 2) ? 64 : 196;
    int Sq = (S + 7) >> 3;
    int s0 = blockIdx.y * Sq, s1 = min(S, s0 + Sq);
    const float4* f = (const float4*)(((mod == 0) ? f0 : (mod == 1) ? f1 : f2) + ((size_t)b * S) * R) + d4;
    const float* wb = e3 + ((mod == 0) ? 0 : (mod == 1) ? 25088 : 50176) + (size_t)b * S;
    float4 acc = {0.f, 0.f, 0.f, 0.f};
#pragma unroll 4
    for (int s = s0; s < s1; ++s) {
        float w = wb[s];
        float4 fv = f[(size_t)s * 256];
        acc.x = fmaf(w, fv.x, acc.x); acc.y = fmaf(w, fv.y, acc.y);
        acc.z = fmaf(w, fv.z, acc.z); acc.w = fmaf(w, fv.w, acc.w);
    }
    float* dst = lang_in + (size_t)b * 4096 + 1024 + mod * 1024 + d4 * 4;
    atomicAdd(dst + 0, acc.x); atomicAdd(dst + 1, acc.y);
    atomicAdd(dst + 2, acc.z); atomicAdd(dst + 3, acc.w);
}

// fr = relu(fr_raw + frb); ho = tanh(ho_raw + hob); zero ct_acc
__global__ __launch_bounds__(256) void relutanh_kernel(
    float* __restrict__ fr, const float* __restrict__ frb,
    float* __restrict__ ho, const float* __restrict__ hob,
    float* __restrict__ ct_acc)
{
    int idx = blockIdx.x * 256 + threadIdx.x;
    int c = idx & 1023;
    if (idx < 131072) { fr[idx] = fmaxf(fr[idx] + frb[c], 0.0f); ct_acc[idx] = 0.0f; }
    else { int i = idx - 131072; ho[i] = tanhf(ho[i] + hob[c]); }
}

// softmax over 197 with fused slot-0 compute
__global__ __launch_bounds__(256) void softmax_ada_kernel(
    float* __restrict__ e,
    const float* __restrict__ fre, const float* __restrict__ frb,
    const float* __restrict__ hoe, const float* __restrict__ hob,
    const float* __restrict__ aw)
{
    __shared__ float red[256];
    int b = blockIdx.x, tid = threadIdx.x;
    float s = 0.0f;
#pragma unroll
    for (int k = 0; k < 4; ++k) {
        int r = k * 256 + tid;
        s += tanhf(fre[(size_t)b * R + r] + frb[r] + hoe[(size_t)b * R + r] + hob[r]) * aw[r];
    }
    red[tid] = s; __syncthreads();
    for (int t = 128; t; t >>= 1) { if (tid < t) red[tid] += red[tid + t]; __syncthreads(); }
    float e0 = red[0]; __syncthreads();
    float v = (tid == 0) ? e0 : ((tid < 197) ? e[(size_t)b * 197 + tid] : -3.4e38f);
    red[tid] = v; __syncthreads();
    for (int t = 128; t; t >>= 1) { if (tid < t) red[tid] = fmaxf(red[tid], red[tid + t]); __syncthreads(); }
    float m = red[0]; __syncthreads();
    float p = (tid < 197) ? __expf(v - m) : 0.0f;
    red[tid] = p; __syncthreads();
    for (int t = 128; t; t >>= 1) { if (tid < t) red[tid] += red[tid + t]; __syncthreads(); }
    float s1 = red[0];
    if (tid < 197) e[(size_t)b * 197 + tid] = p / s1;
}

// c_t_hat partial: ct_acc += sum_{s in chunk of 14} PI[1+s]*attf  (atomic)
__global__ __launch_bounds__(256) void ct_part_kernel(
    const float* __restrict__ PI, const float* __restrict__ attf,
    float* __restrict__ ct_acc)
{
    int b = blockIdx.x, d4 = threadIdx.x;
    int s0 = blockIdx.y * 14, s1 = min(196, s0 + 14);
    const float* pb = PI + b * 197;
    const float4* af = (const float4*)(attf + ((size_t)b * 196) * R) + d4;
    float4 acc = {0.f, 0.f, 0.f, 0.f};
#pragma unroll 2
    for (int s = s0; s < s1; ++s) {
        float w = pb[1 + s];
        float4 av = af[(size_t)s * 256];
        acc.x = fmaf(w, av.x, acc.x); acc.y = fmaf(w, av.y, acc.y);
        acc.z = fmaf(w, av.z, acc.z); acc.w = fmaf(w, av.w, acc.w);
    }
    float* dst = ct_acc + (size_t)b * 1024 + d4 * 4;
    atomicAdd(dst + 0, acc.x); atomicAdd(dst + 1, acc.y);
    atomicAdd(dst + 2, acc.z); atomicAdd(dst + 3, acc.w);
}

// ct = beta*fr + (1-beta)*(PI[0]*fr + ct_acc)
__global__ __launch_bounds__(256) void ct_fin_kernel(
    const float* __restrict__ PI, const float* __restrict__ fr,
    const float* __restrict__ ct_acc, float* __restrict__ ct)
{
    int idx = blockIdx.x * 256 + threadIdx.x;
    int b = idx >> 10;
    const float* pb = PI + b * 197;
    float f = fr[idx];
    float acc = pb[0] * f + ct_acc[idx];
    float beta = pb[196];
    ct[idx] = beta * f + (1.0f - beta) * acc;
}

extern "C" void kernel_launch(void* const* d_in, const int* in_sizes, int n_in,
                              void* d_out, int out_size, void* d_ws, size_t ws_size,
                              hipStream_t stream)
{
    const float* xt         = (const float*)d_in[0];
    const float* state_h    = (const float*)d_in[1];
    const float* state_c    = (const float*)d_in[2];
    const float* fc_feats   = (const float*)d_in[3];
    const float* att_feats  = (const float*)d_in[4];
    const float* obj_feats  = (const float*)d_in[5];
    const float* attr_feats = (const float*)d_in[6];
    const float* rela_feats = (const float*)d_in[7];
    const float* p_obj      = (const float*)d_in[8];
    const float* p_attr     = (const float*)d_in[9];
    const float* p_rela     = (const float*)d_in[10];
    const float* att_masks  = (const float*)d_in[11];
    const float* rela_masks = (const float*)d_in[12];
    const float* att_wih    = (const float*)d_in[13];
    const float* att_whh    = (const float*)d_in[14];
    const float* att_bih    = (const float*)d_in[15];
    const float* att_bhh    = (const float*)d_in[16];
    const float* lang_wih   = (const float*)d_in[17];
    const float* lang_whh   = (const float*)d_in[18];
    const float* lang_bih   = (const float*)d_in[19];
    const float* lang_bhh   = (const float*)d_in[20];
    const float* xt2_w      = (const float*)d_in[21];
    const float* xt2_b      = (const float*)d_in[22];
    const float* h_att2_w   = (const float*)d_in[23];
    const float* h_att2_b   = (const float*)d_in[24];
    const float* r_i2h_w    = (const float*)d_in[25];
    const float* r_i2h_b    = (const float*)d_in[26];
    const float* r_h2h_w    = (const float*)d_in[27];
    const float* r_h2h_b    = (const float*)d_in[28];
    const float* huu_w      = (const float*)d_in[29];
    const float* huu_b      = (const float*)d_in[30];
    const float* obj_h2att_w  = (const float*)d_in[31];
    const float* obj_h2att_b  = (const float*)d_in[32];
    const float* obj_alpha_w  = (const float*)d_in[33];
    const float* attr_h2att_w = (const float*)d_in[35];
    const float* attr_h2att_b = (const float*)d_in[36];
    const float* attr_alpha_w = (const float*)d_in[37];
    const float* rela_h2att_w = (const float*)d_in[39];
    const float* rela_h2att_b = (const float*)d_in[40];
    const float* rela_alpha_w = (const float*)d_in[41];
    const float* fr_lin_w   = (const float*)d_in[43];
    const float* fr_lin_b   = (const float*)d_in[44];
    const float* fr_emb_w   = (const float*)d_in[45];
    const float* fr_emb_b   = (const float*)d_in[46];
    const float* ho_lin_w   = (const float*)d_in[47];
    const float* ho_lin_b   = (const float*)d_in[48];
    const float* ho_emb_w   = (const float*)d_in[49];
    const float* ho_emb_b   = (const float*)d_in[50];
    const float* ada_w      = (const float*)d_in[51];
    const float* cfe_w      = (const float*)d_in[53];
    const float* cfe_b      = (const float*)d_in[54];

    float* out = (float*)d_out;
    float* wsf = (float*)d_ws;

    // ---- ws layout (floats). [0, NATOM) = atomic targets, zeroed upfront.
    float* g        = wsf + 0;         // 128x4096
    float* lang_in  = wsf + 524288;    // 128x4096 [h_att|obj|attr|rela]
    float* att_h3   = wsf + 1048576;   // 3 x 128x512
    float* n5       = wsf + 1245184;   // 128x1024
    float* fr       = wsf + 1376256;   // 128x1024
    float* fre      = wsf + 1507328;   // 128x1024
    float* ho       = wsf + 1638400;   // 128x1024
    float* hoe      = wsf + 1769472;   // 128x1024
    float* e_ada    = wsf + 1900544;   // 128x197 (atomic, pad 25600)
    const int NATOM = 1926144;
    float* att_in    = wsf + 1926144;  // 128x3072 (dead after step 2)
    float* ct_acc    = att_in;         // alias: zeroed in relutanh
    float* h_att_raw = wsf + 2319360;  // 128x1024
    float* e3        = wsf + 2450432;  // 58368 (pad 76800)
    float* st        = wsf + 2527232;  // 128x1024
    float* ct        = wsf + 2658304;  // 128x1024
    short* Pbf       = (short*)(wsf + 2789376);   // 12845056 bf16, FRAGMENT order
    short* Wbf       = Pbf + 12845056;            // 524288 bf16, fragment order
    const bool big = ws_size >= (size_t)2789376 * 4 + (size_t)13369344 * 2;

    float* h_att_out  = out + 131072;
    float* h_lang_out = out + 262144;
    float* c_att_out  = out + 393216;
    float* c_lang_out = out + 524288;

    const float* prev_h = state_h + 131072;

    GJob Z = {};
    auto mk = [&](const float* A1, int lda1, int K1, const float* W1, int ldw1,
                  float* C, int ldc, int N, int Ktot, int Kchunk) {
        GJob j = Z;
        j.A1 = A1; j.lda1 = lda1; j.K1 = K1; j.K12 = Ktot; j.Ktot = Ktot;
        j.W1 = W1; j.ldw1 = ldw1;
        j.C = C; j.ldc = ldc; j.Kchunk = Kchunk; j.nb = N / 64;
        return j;
    };

    // 1. fused prologue: zero + out-bias + concat3 + fragment-order tobf16
    {
        const int ZB = (NATOM + 131072) / 256;          // 8036
        int grid = ZB + 384 + (big ? 6528 : 0);
        prologue_kernel<<<grid, 256, 0, stream>>>(wsf, NATOM, out, huu_b,
            prev_h, fc_feats, xt, att_in, p_obj, cfe_w, Pbf, Wbf, ZB);
    }

    // 2. att-LSTM gates  (SK=8)
    {
        GJob j = mk(att_in, 3072, 3072, att_wih, 3072, g, 4096, 4096, 4096, 512);
        j.A2 = state_h; j.lda2 = 1024; j.W2 = att_whh; j.ldw2 = 1024; j.K12 = 4096;
        gemm_sk_kernel<<<dim3(64, 8), 256, 0, stream>>>(j, Z, Z, 1);
    }
    // 3. att LSTM cell
    lstm_kernel<<<128, 256, 0, stream>>>(g, att_bih, att_bhh, state_c, h_att_raw, c_att_out,
                                         nullptr, nullptr, nullptr, nullptr);

    // 4. h_att -> lang_in col 0  (SK=16)
    {
        GJob j = mk(xt, 1024, 1024, xt2_w, 1024, lang_in, 4096, 1024, 2048, 128);
        j.A2 = h_att_raw; j.lda2 = 1024; j.W2 = h_att2_w; j.ldw2 = 1024; j.K12 = 2048;
        gemm_sk_kernel<<<dim3(16, 16), 256, 0, stream>>>(j, Z, Z, 1);
    }
    // 5. h_att bias + copy out
    hatt_epi_kernel<<<128, 256, 0, stream>>>(lang_in, xt2_b, h_att2_b, h_att_out);

    // 6. three h2att GEMMs in one launch (SK=16)
    {
        GJob j0 = mk(lang_in, 4096, 1024, obj_h2att_w,  1024, att_h3 + 0,      512, 512, 1024, 64);
        GJob j1 = mk(lang_in, 4096, 1024, attr_h2att_w, 1024, att_h3 + 65536,  512, 512, 1024, 64);
        GJob j2 = mk(lang_in, 4096, 1024, rela_h2att_w, 1024, att_h3 + 131072, 512, 512, 1024, 64);
        gemm_sk_kernel<<<dim3(24, 16), 256, 0, stream>>>(j0, j1, j2, 3);
    }
    // 7-9. fused e / softmax / wsum (s-split x8)
    att_e3_kernel<<<14592, 256, 0, stream>>>(p_obj, p_attr, p_rela, att_h3,
        obj_h2att_b, attr_h2att_b, rela_h2att_b, obj_alpha_w, attr_alpha_w, rela_alpha_w, e3);
    softmax3_kernel<<<384, 256, 0, stream>>>(e3, att_masks, rela_masks);
    wsum3_kernel<<<dim3(384, 8), 256, 0, stream>>>(e3, obj_feats, attr_feats, rela_feats, lang_in);

    // 10. lang gates + n5 (share A) in one launch (SK=8)
    {
        GJob j0 = mk(lang_in, 4096, 4096, lang_wih, 4096, g, 4096, 4096, 5120, 640);
        j0.A2 = prev_h; j0.lda2 = 1024; j0.W2 = lang_whh; j0.ldw2 = 1024; j0.K12 = 5120;
        GJob j1 = mk(lang_in, 4096, 4096, r_i2h_w, 4096, n5, 1024, 1024, 5120, 640);
        j1.A2 = prev_h; j1.lda2 = 1024; j1.W2 = r_h2h_w; j1.ldw2 = 1024; j1.K12 = 5120;
        gemm_sk_kernel<<<dim3(80, 8), 256, 0, stream>>>(j0, j1, Z, 2);
    }
    // 11. lang LSTM cell + st fused
    lstm_kernel<<<128, 256, 0, stream>>>(g, lang_bih, lang_bhh, state_c + 131072,
                                         h_lang_out, c_lang_out, n5, r_i2h_b, r_h2h_b, st);

    // 12. fr + ho GEMMs (SK=16)
    {
        GJob j0 = mk(st, 1024, 1024, fr_lin_w, 1024, fr, 1024, 1024, 1024, 64);
        GJob j1 = mk(h_lang_out, 1024, 1024, ho_lin_w, 1024, ho, 1024, 1024, 1024, 64);
        gemm_sk_kernel<<<dim3(32, 16), 256, 0, stream>>>(j0, j1, Z, 2);
    }
    // 13. relu/tanh epilogue + zero ct_acc
    relutanh_kernel<<<1024, 256, 0, stream>>>(fr, fr_lin_b, ho, ho_lin_b, ct_acc);

    // 14. fre + hoe GEMMs (SK=16; biases folded downstream)
    {
        GJob j0 = mk(fr, 1024, 1024, fr_emb_w, 1024, fre, 1024, 1024, 1024, 64);
        GJob j1 = mk(ho, 1024, 1024, ho_emb_w, 1024, hoe, 1024, 1024, 1024, 64);
        gemm_sk_kernel<<<dim3(32, 16), 256, 0, stream>>>(j0, j1, Z, 2);
    }
    // 15. cfe -> e_ada[1..196]
    if (big) {
        cfe_v6_kernel<<<1600, 256, 0, stream>>>(Pbf, Wbf, cfe_b, hoe, ho_emb_b, ada_w, e_ada);
    } else {
        cfe_fallback_kernel<<<1600, 256, 0, stream>>>(p_obj, cfe_w, cfe_b, hoe, ho_emb_b, ada_w, e_ada);
    }
    // 16. adaptive softmax (fused slot-0)
    softmax_ada_kernel<<<128, 256, 0, stream>>>(e_ada, fre, fr_emb_b, hoe, ho_emb_b, ada_w);
    // 17-18. c_t_hat
    ct_part_kernel<<<dim3(128, 14), 256, 0, stream>>>(e_ada, att_feats, ct_acc);
    ct_fin_kernel<<<512, 256, 0, stream>>>(e_ada, fr, ct_acc, ct);

    // 19. output = [h_att | h_lang | c_t_hat] @ huu^T (bias pre-initialized, SK=16)
    {
        GJob j = mk(lang_in, 4096, 1024, huu_w, 3072, out, 1024, 1024, 3072, 192);
        j.A2 = h_lang_out; j.lda2 = 1024; j.W2 = huu_w + 1024; j.ldw2 = 3072; j.K12 = 2048;
        j.A3 = ct; j.lda3 = 1024; j.W3 = huu_w + 2048; j.ldw3 = 3072;
        gemm_sk_kernel<<<dim3(16, 16), 256, 0, stream>>>(j, Z, Z, 1);
    }

    (void)in_sizes; (void)n_in; (void)out_size; (void)ws_size;
}

// Round 10
// 407.823 us; speedup vs baseline: 1.0340x; 1.0340x over previous
//
#include <hip/hip_runtime.h>
#include <cstddef>

#define B 128
#define R 1024

typedef __attribute__((ext_vector_type(8))) short short8;
typedef __attribute__((ext_vector_type(4))) float f32x4;

__device__ __forceinline__ float sigf(float x) { return 1.0f / (1.0f + __expf(-x)); }

__device__ __forceinline__ short f2bf(float f) {
    unsigned int u = __float_as_uint(f);
    u += 0x7fff + ((u >> 16) & 1);   // RNE
    return (short)(u >> 16);
}

__device__ __forceinline__ short8 cvt8(float4 u, float4 v) {
    short8 r;
    r[0] = f2bf(u.x); r[1] = f2bf(u.y); r[2] = f2bf(u.z); r[3] = f2bf(u.w);
    r[4] = f2bf(v.x); r[5] = f2bf(v.y); r[6] = f2bf(v.z); r[7] = f2bf(v.w);
    return r;
}

__device__ __forceinline__ void gll16(const void* g, void* l) {
    __builtin_amdgcn_global_load_lds(
        (const __attribute__((address_space(1))) unsigned int*)g,
        (__attribute__((address_space(3))) unsigned int*)l, 16, 0, 0);
}

// ---------------------------------------------------------------------------
// Split-K multi-job bf16-MFMA GEMM. M=128, BN=64, BK=32, 4 waves (each 32x64).
// C[m,n] += sum_k A[m,k]*W[n,k]  via atomicAdd (C pre-zeroed; bias in epilogue).
// ---------------------------------------------------------------------------
struct GJob {
    const float* A1; const float* A2; const float* A3;
    const float* W1; const float* W2; const float* W3;
    float* C;
    int lda1, lda2, lda3;
    int ldw1, ldw2, ldw3;
    int K1, K12, Ktot;
    int ldc, Kchunk, nb;
};

__global__ __launch_bounds__(256) void gemm_sk_kernel(GJob j0, GJob j1, GJob j2, int njobs)
{
    GJob j = j0;
    int nbx = blockIdx.x;
    if (njobs > 1 && nbx >= j.nb) { nbx -= j.nb; j = j1; }
    if (njobs > 2 && nbx >= j.nb) { nbx -= j.nb; j = j2; }

    const int bn   = nbx * 64;
    const int kbeg = blockIdx.y * j.Kchunk;
    const int kend = kbeg + j.Kchunk;

    __shared__ short sA[128 * 40];
    __shared__ short sB[64 * 40];
    const int tid  = threadIdx.x;
    const int rA   = tid >> 1;
    const int kha  = (tid & 1) << 4;
    const int rB   = tid >> 2;
    const int khb  = (tid & 3) << 3;
    const int lane = tid & 63;
    const int wid  = tid >> 6;
    const int wm   = wid * 32;
    const int fr_  = lane & 15;
    const int kof  = (lane >> 4) * 8;

    f32x4 acc[2][4];
#pragma unroll
    for (int m = 0; m < 2; ++m)
#pragma unroll
        for (int n = 0; n < 4; ++n)
            acc[m][n] = (f32x4)0.0f;

    for (int k0 = kbeg; k0 < kend; k0 += 32) {
        int kgA = k0 + kha;
        const float* pa;
        if (kgA < j.K1)       pa = j.A1 + (size_t)rA * j.lda1 + kgA;
        else if (kgA < j.K12) pa = j.A2 + (size_t)rA * j.lda2 + (kgA - j.K1);
        else                  pa = j.A3 + (size_t)rA * j.lda3 + (kgA - j.K12);
        int kgB = k0 + khb;
        const float* pw;
        if (kgB < j.K1)       pw = j.W1 + (size_t)(bn + rB) * j.ldw1 + kgB;
        else if (kgB < j.K12) pw = j.W2 + (size_t)(bn + rB) * j.ldw2 + (kgB - j.K1);
        else                  pw = j.W3 + (size_t)(bn + rB) * j.ldw3 + (kgB - j.K12);

        float4 a0 = ((const float4*)pa)[0];
        float4 a1 = ((const float4*)pa)[1];
        float4 a2 = ((const float4*)pa)[2];
        float4 a3 = ((const float4*)pa)[3];
        float4 w0 = ((const float4*)pw)[0];
        float4 w1 = ((const float4*)pw)[1];
        __syncthreads();
        *(short8*)&sA[rA * 40 + kha]     = cvt8(a0, a1);
        *(short8*)&sA[rA * 40 + kha + 8] = cvt8(a2, a3);
        *(short8*)&sB[rB * 40 + khb]     = cvt8(w0, w1);
        __syncthreads();
        short8 af[2], bf[4];
#pragma unroll
        for (int m = 0; m < 2; ++m)
            af[m] = *(const short8*)&sA[(wm + m * 16 + fr_) * 40 + kof];
#pragma unroll
        for (int n = 0; n < 4; ++n)
            bf[n] = *(const short8*)&sB[(n * 16 + fr_) * 40 + kof];
#pragma unroll
        for (int m = 0; m < 2; ++m)
#pragma unroll
            for (int n = 0; n < 4; ++n)
                acc[m][n] = __builtin_amdgcn_mfma_f32_16x16x32_bf16(af[m], bf[n], acc[m][n], 0, 0, 0);
    }

#pragma unroll
    for (int m = 0; m < 2; ++m) {
        int row0 = wm + m * 16 + ((lane >> 4) << 2);
#pragma unroll
        for (int n = 0; n < 4; ++n) {
            int col = bn + n * 16 + fr_;
#pragma unroll
            for (int rg = 0; rg < 4; ++rg)
                atomicAdd(&j.C[(size_t)(row0 + rg) * j.ldc + col], acc[m][n][rg]);
        }
    }
}

// ---------------------------------------------------------------------------
// Fused prologue. Blocks:
//  [0,ZB): zero atomic ws + init out bias
//  [ZB,ZB+384): concat3 -> att_in
//  [ZB+384, +6272): P -> Pbf in FRAGMENT order (wave per (rt,ks))
//  [ZB+6656, +256): cfe_w -> Wbf in fragment order
// Fragment f = rt*16+ks is 1KB contiguous: element (f*64+lane)*8, where
// lane = (kgroup<<4)|row_in_tile matches the MFMA A/B fragment layout.
// ---------------------------------------------------------------------------
__global__ __launch_bounds__(256) void prologue_kernel(
    float* __restrict__ ws, int nws, float* __restrict__ o, const float* __restrict__ bias,
    const float* __restrict__ ph, const float* __restrict__ fc, const float* __restrict__ xt,
    float* __restrict__ att_in,
    const float* __restrict__ P, const float* __restrict__ W,
    short* __restrict__ Pbf, short* __restrict__ Wbf, int ZB)
{
    int blk = blockIdx.x;
    int tid = threadIdx.x;
    if (blk < ZB) {
        int idx = blk * 256 + tid;
        if (idx < nws) ws[idx] = 0.0f;
        else if (idx < nws + 131072) { int i = idx - nws; o[i] = bias[i & 1023]; }
        return;
    }
    blk -= ZB;
    if (blk < 384) {
        int idx = blk * 256 + tid;
        int r = idx / 768, c4 = idx - r * 768;
        int col = c4 * 4;
        const float* src = (col < 1024) ? (ph + (size_t)r * 1024 + col)
                         : (col < 2048) ? (fc + (size_t)r * 1024 + col - 1024)
                                        : (xt + (size_t)r * 1024 + col - 2048);
        *(float4*)(att_in + (size_t)r * 3072 + col) = *(const float4*)src;
        return;
    }
    blk -= 384;
    int lane = tid & 63;
    int fr = lane & 15, kg = lane >> 4;
    if (blk < 6272) {
        int w = blk * 4 + (tid >> 6);     // 0..25087 = rt*16+ks
        int rt = w >> 4, ks = w & 15;
        const float* src = P + (size_t)(rt * 16 + fr) * 512 + ks * 32 + kg * 8;
        float4 u = ((const float4*)src)[0];
        float4 v = ((const float4*)src)[1];
        *(short8*)(Pbf + ((size_t)w * 64 + lane) * 8) = cvt8(u, v);
    } else {
        int w = (blk - 6272) * 4 + (tid >> 6);   // 0..1023 = ct*16+ks
        int ct = w >> 4, ks = w & 15;
        const float* src = W + (size_t)(ct * 16 + fr) * 512 + ks * 32 + kg * 8;
        float4 u = ((const float4*)src)[0];
        float4 v = ((const float4*)src)[1];
        *(short8*)(Wbf + ((size_t)w * 64 + lane) * 8) = cvt8(u, v);
    }
}

// ---------------------------------------------------------------------------
// cfe v7: m97-structure. Fragment-ordered Pbf/Wbf staged to LDS via
// global_load_lds (linear dest, 1KB/frag), double-buffered, BK=32 (1 frag-col
// per round). LDS reads are lane-contiguous (2-way alias = free). LDS 32KB ->
// ~4 blocks/CU. Operand sharing halves L2 traffic vs reg-blocked v5/v6.
// ---------------------------------------------------------------------------
__global__ __launch_bounds__(256) void cfe_v7_kernel(
    const short* __restrict__ Pbf, const short* __restrict__ Wbf,
    const float* __restrict__ cb, const float* __restrict__ hoe,
    const float* __restrict__ ho_b, const float* __restrict__ aw,
    float* __restrict__ e)
{
    int p = blockIdx.x;
    int x8 = p & 7, rest = p >> 3;
    int n8 = rest & 7, q = rest >> 3;
    int m = q * 8 + x8;
    if (m >= 196) return;
    const int bm = m * 128, bn = n8 * 128;

    __shared__ short sA[2][8 * 512];   // 8 frags x 1KB per buffer
    __shared__ short sB[2][8 * 512];

    const int tid  = threadIdx.x;
    const int lane = tid & 63;
    const int wid  = tid >> 6;
    const int wm   = (wid >> 1) * 64;
    const int wn   = (wid & 1) * 64;
    const int fr_  = lane & 15;
    const int rtbA = bm >> 4;          // global 16-row tile base for A
    const int rtbB = bn >> 4;          // for B

    // wave stages frags fid = wid*4 .. wid*4+3 of the 16 per round
    // fid: 0..7 -> A rt=fid; 8..15 -> B rt=fid-7... (fid&7)
    auto STAGE = [&](int buf, int ks) {
#pragma unroll
        for (int jj = 0; jj < 4; ++jj) {
            int fid = wid * 4 + jj;
            int rt  = fid & 7;
            if (fid < 8) {
                const short* src = Pbf + ((size_t)((rtbA + rt) * 16 + ks) * 64 + lane) * 8;
                gll16(src, &sA[buf][rt * 512]);
            } else {
                const short* src = Wbf + ((size_t)((rtbB + rt) * 16 + ks) * 64 + lane) * 8;
                gll16(src, &sB[buf][rt * 512]);
            }
        }
    };

    f32x4 acc[4][4];
#pragma unroll
    for (int mi = 0; mi < 4; ++mi)
#pragma unroll
        for (int n = 0; n < 4; ++n)
            acc[mi][n] = (f32x4)0.0f;

    STAGE(0, 0);
    for (int r = 0; r < 16; ++r) {
        const int buf = r & 1;
        __syncthreads();                       // staged buf ready (vmcnt drained)
        if (r < 15) STAGE(buf ^ 1, r + 1);     // prefetch next under compute
        short8 af[4], bf8[4];
#pragma unroll
        for (int mi = 0; mi < 4; ++mi)
            af[mi] = *(const short8*)&sA[buf][((wm >> 4) + mi) * 512 + lane * 8];
#pragma unroll
        for (int n = 0; n < 4; ++n)
            bf8[n] = *(const short8*)&sB[buf][((wn >> 4) + n) * 512 + lane * 8];
#pragma unroll
        for (int mi = 0; mi < 4; ++mi)
#pragma unroll
            for (int n = 0; n < 4; ++n)
                acc[mi][n] = __builtin_amdgcn_mfma_f32_16x16x32_bf16(af[mi], bf8[n], acc[mi][n], 0, 0, 0);
        __syncthreads();                       // reads done before next overwrite
    }

    // epilogue: per-row tanh-dot, shfl reduce over 16 lanes, atomic add
    const int l4 = lane >> 4;
    const int rbase = bm + wm + (l4 << 2);
    const int b0 = rbase / 196;
    const int b1 = (rbase + 51) / 196;
    float cba[4], awa[4], hv0[4], hv1[4];
#pragma unroll
    for (int n = 0; n < 4; ++n) {
        int col = bn + wn + n * 16 + fr_;
        cba[n] = cb[col] + ho_b[col];
        awa[n] = aw[col];
        hv0[n] = hoe[(size_t)b0 * R + col];
        hv1[n] = hoe[(size_t)b1 * R + col];
    }
#pragma unroll
    for (int mi = 0; mi < 4; ++mi) {
#pragma unroll
        for (int rg = 0; rg < 4; ++rg) {
            int gr = rbase + mi * 16 + rg;
            int bb = gr / 196;
            bool second = (bb != b0);
            float part = 0.0f;
#pragma unroll
            for (int n = 0; n < 4; ++n) {
                float hv = second ? hv1[n] : hv0[n];
                part += tanhf(acc[mi][n][rg] + cba[n] + hv) * awa[n];
            }
            part += __shfl_xor(part, 1);
            part += __shfl_xor(part, 2);
            part += __shfl_xor(part, 4);
            part += __shfl_xor(part, 8);
            if (fr_ == 0)
                atomicAdd(&e[bb * 197 + 1 + (gr - bb * 196)], part);
        }
    }
}

// fallback (ws too small for Pbf): fp32 inputs + in-kernel cvt, LDS staged
__global__ __launch_bounds__(256) void cfe_fallback_kernel(
    const float* __restrict__ P, const float* __restrict__ Wf,
    const float* __restrict__ cb, const float* __restrict__ hoe,
    const float* __restrict__ ho_b, const float* __restrict__ aw,
    float* __restrict__ e)
{
    int p = blockIdx.x;
    int x8 = p & 7, rest = p >> 3;
    int n8 = rest & 7, q = rest >> 3;
    int m = q * 8 + x8;
    if (m >= 196) return;
    const int bm = m * 128, bn = n8 * 128;

    __shared__ short sA[128 * 72];
    __shared__ short sB[128 * 72];
    const int tid  = threadIdx.x;
    const int lane = tid & 63;
    const int wid  = tid >> 6;
    const int wm   = (wid >> 1) * 64;
    const int wn   = (wid & 1) * 64;
    const int fr_  = lane & 15;
    const int kof  = (lane >> 4) * 8;

    f32x4 acc[4][4];
#pragma unroll
    for (int mi = 0; mi < 4; ++mi)
#pragma unroll
        for (int n = 0; n < 4; ++n)
            acc[mi][n] = (f32x4)0.0f;

    for (int k0 = 0; k0 < 512; k0 += 64) {
        __syncthreads();
        int row = tid >> 1;
        int half = (tid & 1) * 32;
        const float* pa = P + (size_t)(bm + row) * 512 + k0 + half;
        const float* pw = Wf + (size_t)(bn + row) * 512 + k0 + half;
#pragma unroll
        for (int c = 0; c < 32; c += 8) {
            float4 u = *(const float4*)(pa + c);
            float4 v = *(const float4*)(pa + c + 4);
            *(short8*)&sA[row * 72 + half + c] = cvt8(u, v);
            float4 uw = *(const float4*)(pw + c);
            float4 vw = *(const float4*)(pw + c + 4);
            *(short8*)&sB[row * 72 + half + c] = cvt8(uw, vw);
        }
        __syncthreads();
#pragma unroll
        for (int ks = 0; ks < 64; ks += 32) {
            short8 af[4], bf[4];
#pragma unroll
            for (int mi = 0; mi < 4; ++mi)
                af[mi] = *(const short8*)&sA[(wm + mi * 16 + fr_) * 72 + ks + kof];
#pragma unroll
            for (int n = 0; n < 4; ++n)
                bf[n] = *(const short8*)&sB[(wn + n * 16 + fr_) * 72 + ks + kof];
#pragma unroll
            for (int mi = 0; mi < 4; ++mi)
#pragma unroll
                for (int n = 0; n < 4; ++n)
                    acc[mi][n] = __builtin_amdgcn_mfma_f32_16x16x32_bf16(af[mi], bf[n], acc[mi][n], 0, 0, 0);
        }
    }

    const int l4 = lane >> 4;
    const int rbase = bm + wm + (l4 << 2);
    const int b0 = rbase / 196;
    const int b1 = (rbase + 51) / 196;
    float cba[4], awa[4], hv0[4], hv1[4];
#pragma unroll
    for (int n = 0; n < 4; ++n) {
        int col = bn + wn + n * 16 + fr_;
        cba[n] = cb[col] + ho_b[col];
        awa[n] = aw[col];
        hv0[n] = hoe[(size_t)b0 * R + col];
        hv1[n] = hoe[(size_t)b1 * R + col];
    }
#pragma unroll
    for (int mi = 0; mi < 4; ++mi) {
#pragma unroll
        for (int rg = 0; rg < 4; ++rg) {
            int gr = rbase + mi * 16 + rg;
            int bb = gr / 196;
            bool second = (bb != b0);
            float part = 0.0f;
#pragma unroll
            for (int n = 0; n < 4; ++n) {
                float hv = second ? hv1[n] : hv0[n];
                part += tanhf(acc[mi][n][rg] + cba[n] + hv) * awa[n];
            }
            part += __shfl_xor(part, 1);
            part += __shfl_xor(part, 2);
            part += __shfl_xor(part, 4);
            part += __shfl_xor(part, 8);
            if (fr_ == 0)
                atomicAdd(&e[bb * 197 + 1 + (gr - bb * 196)], part);
        }
    }
}

// vectorized LSTM epilogue (+ optional st fusion); self-zero g.
__global__ __launch_bounds__(256) void lstm_kernel(
    float* __restrict__ g, const float* __restrict__ bih, const float* __restrict__ bhh,
    const float* __restrict__ cprev, float* __restrict__ h, float* __restrict__ c,
    const float* __restrict__ n5, const float* __restrict__ nb1,
    const float* __restrict__ nb2, float* __restrict__ st)
{
    int t = blockIdx.x * 256 + threadIdx.x;   // 0..32767
    int b = t >> 8, d4 = (t & 255) * 4;
    float* gr = g + (size_t)b * 4096;
    float4 gi = *(float4*)(gr + d4);
    float4 gf = *(float4*)(gr + 1024 + d4);
    float4 gg = *(float4*)(gr + 2048 + d4);
    float4 go = *(float4*)(gr + 3072 + d4);
    float4 bi1 = *(const float4*)(bih + d4),        bh1 = *(const float4*)(bhh + d4);
    float4 bi2 = *(const float4*)(bih + 1024 + d4), bh2 = *(const float4*)(bhh + 1024 + d4);
    float4 bi3 = *(const float4*)(bih + 2048 + d4), bh3 = *(const float4*)(bhh + 2048 + d4);
    float4 bi4 = *(const float4*)(bih + 3072 + d4), bh4 = *(const float4*)(bhh + 3072 + d4);
    float4 cp = *(const float4*)(cprev + (size_t)b * 1024 + d4);
    float4 zero = {0.f, 0.f, 0.f, 0.f};
    *(float4*)(gr + d4) = zero; *(float4*)(gr + 1024 + d4) = zero;
    *(float4*)(gr + 2048 + d4) = zero; *(float4*)(gr + 3072 + d4) = zero;
    float4 cc, hh;
    float iv, fv, gv, ov, c2, tc;
    iv = sigf(gi.x + bi1.x + bh1.x); fv = sigf(gf.x + bi2.x + bh2.x);
    gv = tanhf(gg.x + bi3.x + bh3.x); ov = sigf(go.x + bi4.x + bh4.x);
    c2 = fv * cp.x + iv * gv; tc = tanhf(c2); cc.x = c2; hh.x = ov * tc;
    float tcx = tc;
    iv = sigf(gi.y + bi1.y + bh1.y); fv = sigf(gf.y + bi2.y + bh2.y);
    gv = tanhf(gg.y + bi3.y + bh3.y); ov = sigf(go.y + bi4.y + bh4.y);
    c2 = fv * cp.y + iv * gv; tc = tanhf(c2); cc.y = c2; hh.y = ov * tc;
    float tcy = tc;
    iv = sigf(gi.z + bi1.z + bh1.z); fv = sigf(gf.z + bi2.z + bh2.z);
    gv = tanhf(gg.z + bi3.z + bh3.z); ov = sigf(go.z + bi4.z + bh4.z);
    c2 = fv * cp.z + iv * gv; tc = tanhf(c2); cc.z = c2; hh.z = ov * tc;
    float tcz = tc;
    iv = sigf(gi.w + bi1.w + bh1.w); fv = sigf(gf.w + bi2.w + bh2.w);
    gv = tanhf(gg.w + bi3.w + bh3.w); ov = sigf(go.w + bi4.w + bh4.w);
    c2 = fv * cp.w + iv * gv; tc = tanhf(c2); cc.w = c2; hh.w = ov * tc;
    float tcw = tc;
    *(float4*)(c + (size_t)b * 1024 + d4) = cc;
    *(float4*)(h + (size_t)b * 1024 + d4) = hh;
    if (st) {
        float4 nv = *(const float4*)(n5 + (size_t)b * 1024 + d4);
        float4 n1 = *(const float4*)(nb1 + d4), n2 = *(const float4*)(nb2 + d4);
        float4 sv;
        sv.x = sigf(nv.x + n1.x + n2.x) * tcx;
        sv.y = sigf(nv.y + n1.y + n2.y) * tcy;
        sv.z = sigf(nv.z + n1.z + n2.z) * tcz;
        sv.w = sigf(nv.w + n1.w + n2.w) * tcw;
        *(float4*)(st + (size_t)b * 1024 + d4) = sv;
    }
}

// h_att epilogue: lang_in[:,0:1024] += biases (in place) and copy to h_att_out
__global__ __launch_bounds__(256) void hatt_epi_kernel(
    float* __restrict__ lang_in, const float* __restrict__ b1,
    const float* __restrict__ b2, float* __restrict__ h_att_out)
{
    int t = blockIdx.x * 256 + threadIdx.x;   // 0..32767
    int r = t >> 8, c4 = (t & 255) * 4;
    float4 v = *(float4*)(lang_in + (size_t)r * 4096 + c4);
    float4 x1 = *(const float4*)(b1 + c4), x2 = *(const float4*)(b2 + c4);
    v.x += x1.x + x2.x; v.y += x1.y + x2.y; v.z += x1.z + x2.z; v.w += x1.w + x2.w;
    *(float4*)(lang_in + (size_t)r * 4096 + c4) = v;
    *(float4*)(h_att_out + (size_t)r * 1024 + c4) = v;
}

// fused 3-module e (float4, coalesced): e[item] = sum_a tanh(p + ah + b2) * aw
__global__ __launch_bounds__(256) void att_e3_kernel(
    const float* __restrict__ p0, const float* __restrict__ p1, const float* __restrict__ p2,
    const float* __restrict__ ah3,
    const float* __restrict__ b0, const float* __restrict__ b1, const float* __restrict__ b2,
    const float* __restrict__ aw0, const float* __restrict__ aw1, const float* __restrict__ aw2,
    float* __restrict__ e3)
{
    int wid = threadIdx.x >> 6, lane = threadIdx.x & 63;
    int idx = blockIdx.x * 4 + wid;
    const float* p; const float* bb; const float* aw; int S, loc, mod;
    if (idx < 25088)      { mod = 0; loc = idx;          p = p0; bb = b0; aw = aw0; S = 196; }
    else if (idx < 50176) { mod = 1; loc = idx - 25088;  p = p1; bb = b1; aw = aw1; S = 196; }
    else                  { mod = 2; loc = idx - 50176;  p = p2; bb = b2; aw = aw2; S = 64; }
    int b = loc / S;
    const float4* pr = (const float4*)(p + (size_t)loc * 512);
    const float4* ab = (const float4*)(ah3 + (size_t)mod * 65536 + (size_t)b * 512);
    const float4* bb4 = (const float4*)bb;
    const float4* aw4 = (const float4*)aw;
    float sum = 0.0f;
#pragma unroll
    for (int k = 0; k < 2; ++k) {
        int a = k * 64 + lane;
        float4 pv = pr[a], av = ab[a], bv = bb4[a], wv = aw4[a];
        sum += tanhf(pv.x + av.x + bv.x) * wv.x;
        sum += tanhf(pv.y + av.y + bv.y) * wv.y;
        sum += tanhf(pv.z + av.z + bv.z) * wv.z;
        sum += tanhf(pv.w + av.w + bv.w) * wv.w;
    }
#pragma unroll
    for (int off = 32; off; off >>= 1) sum += __shfl_down(sum, off);
    if (lane == 0) e3[idx] = sum;
}

// fused 3-module softmax (mask + renorm), in place on e3
__global__ __launch_bounds__(256) void softmax3_kernel(
    float* __restrict__ e3, const float* __restrict__ am, const float* __restrict__ rm)
{
    __shared__ float red[256];
    int mod = blockIdx.x >> 7, b = blockIdx.x & 127, tid = threadIdx.x;
    int S = (mod == 2) ? 64 : 196;
    float* e = e3 + ((mod == 0) ? 0 : (mod == 1) ? 25088 : 50176) + (size_t)b * S;
    const float* mask = ((mod == 2) ? rm : am) + (size_t)b * S;
    float v = (tid < S) ? e[tid] : -3.4e38f;
    red[tid] = v; __syncthreads();
    for (int s = 128; s; s >>= 1) { if (tid < s) red[tid] = fmaxf(red[tid], red[tid + s]); __syncthreads(); }
    float m = red[0]; __syncthreads();
    float p = (tid < S) ? __expf(v - m) : 0.0f;
    red[tid] = p; __syncthreads();
    for (int s = 128; s; s >>= 1) { if (tid < s) red[tid] += red[tid + s]; __syncthreads(); }
    float s1 = red[0]; __syncthreads();
    float w = (tid < S) ? (p / s1) * mask[tid] : 0.0f;
    red[tid] = w; __syncthreads();
    for (int s = 128; s; s >>= 1) { if (tid < s) red[tid] += red[tid + s]; __syncthreads(); }
    float s2 = red[0];
    if (tid < S) e[tid] = w / s2;
}

// fused 3-module weighted sum, s-split x4, atomic into lang_in (zeroed)
__global__ __launch_bounds__(256) void wsum3_kernel(
    const float* __restrict__ e3,
    const float* __restrict__ f0, const float* __restrict__ f1, const float* __restrict__ f2,
    float* __restrict__ lang_in)
{
    int mod = blockIdx.x >> 7;
    int idx = (blockIdx.x & 127) * 256 + threadIdx.x;
    int b = idx >> 8, d4 = idx & 255;
    int S = (mod == 2) ? 64 : 196;
    int Sq = (S + 3) >> 2;
    int s0 = blockIdx.y * Sq, s1 = min(S, s0 + Sq);
    const float4* f = (const float4*)(((mod == 0) ? f0 : (mod == 1) ? f1 : f2) + ((size_t)b * S) * R) + d4;
    const float* wb = e3 + ((mod == 0) ? 0 : (mod == 1) ? 25088 : 50176) + (size_t)b * S;
    float4 acc = {0.f, 0.f, 0.f, 0.f};
#pragma unroll 4
    for (int s = s0; s < s1; ++s) {
        float w = wb[s];
        float4 fv = f[(size_t)s * 256];
        acc.x = fmaf(w, fv.x, acc.x); acc.y = fmaf(w, fv.y, acc.y);
        acc.z = fmaf(w, fv.z, acc.z); acc.w = fmaf(w, fv.w, acc.w);
    }
    float* dst = lang_in + (size_t)b * 4096 + 1024 + mod * 1024 + d4 * 4;
    atomicAdd(dst + 0, acc.x); atomicAdd(dst + 1, acc.y);
    atomicAdd(dst + 2, acc.z); atomicAdd(dst + 3, acc.w);
}

// fr = relu(fr_raw + frb); ho = tanh(ho_raw + hob); zero ct_acc
__global__ __launch_bounds__(256) void relutanh_kernel(
    float* __restrict__ fr, const float* __restrict__ frb,
    float* __restrict__ ho, const float* __restrict__ hob,
    float* __restrict__ ct_acc)
{
    int idx = blockIdx.x * 256 + threadIdx.x;
    int c = idx & 1023;
    if (idx < 131072) { fr[idx] = fmaxf(fr[idx] + frb[c], 0.0f); ct_acc[idx] = 0.0f; }
    else { int i = idx - 131072; ho[i] = tanhf(ho[i] + hob[c]); }
}

// softmax over 197 with fused slot-0 compute
__global__ __launch_bounds__(256) void softmax_ada_kernel(
    float* __restrict__ e,
    const float* __restrict__ fre, const float* __restrict__ frb,
    const float* __restrict__ hoe, const float* __restrict__ hob,
    const float* __restrict__ aw)
{
    __shared__ float red[256];
    int b = blockIdx.x, tid = threadIdx.x;
    float s = 0.0f;
#pragma unroll
    for (int k = 0; k < 4; ++k) {
        int r = k * 256 + tid;
        s += tanhf(fre[(size_t)b * R + r] + frb[r] + hoe[(size_t)b * R + r] + hob[r]) * aw[r];
    }
    red[tid] = s; __syncthreads();
    for (int t = 128; t; t >>= 1) { if (tid < t) red[tid] += red[tid + t]; __syncthreads(); }
    float e0 = red[0]; __syncthreads();
    float v = (tid == 0) ? e0 : ((tid < 197) ? e[(size_t)b * 197 + tid] : -3.4e38f);
    red[tid] = v; __syncthreads();
    for (int t = 128; t; t >>= 1) { if (tid < t) red[tid] = fmaxf(red[tid], red[tid + t]); __syncthreads(); }
    float m = red[0]; __syncthreads();
    float p = (tid < 197) ? __expf(v - m) : 0.0f;
    red[tid] = p; __syncthreads();
    for (int t = 128; t; t >>= 1) { if (tid < t) red[tid] += red[tid + t]; __syncthreads(); }
    float s1 = red[0];
    if (tid < 197) e[(size_t)b * 197 + tid] = p / s1;
}

// c_t_hat partial: ct_acc += sum_{s in chunk of 14} PI[1+s]*attf  (atomic)
__global__ __launch_bounds__(256) void ct_part_kernel(
    const float* __restrict__ PI, const float* __restrict__ attf,
    float* __restrict__ ct_acc)
{
    int b = blockIdx.x, d4 = threadIdx.x;
    int s0 = blockIdx.y * 14, s1 = min(196, s0 + 14);
    const float* pb = PI + b * 197;
    const float4* af = (const float4*)(attf + ((size_t)b * 196) * R) + d4;
    float4 acc = {0.f, 0.f, 0.f, 0.f};
#pragma unroll 2
    for (int s = s0; s < s1; ++s) {
        float w = pb[1 + s];
        float4 av = af[(size_t)s * 256];
        acc.x = fmaf(w, av.x, acc.x); acc.y = fmaf(w, av.y, acc.y);
        acc.z = fmaf(w, av.z, acc.z); acc.w = fmaf(w, av.w, acc.w);
    }
    float* dst = ct_acc + (size_t)b * 1024 + d4 * 4;
    atomicAdd(dst + 0, acc.x); atomicAdd(dst + 1, acc.y);
    atomicAdd(dst + 2, acc.z); atomicAdd(dst + 3, acc.w);
}

// ct = beta*fr + (1-beta)*(PI[0]*fr + ct_acc)
__global__ __launch_bounds__(256) void ct_fin_kernel(
    const float* __restrict__ PI, const float* __restrict__ fr,
    const float* __restrict__ ct_acc, float* __restrict__ ct)
{
    int idx = blockIdx.x * 256 + threadIdx.x;
    int b = idx >> 10;
    const float* pb = PI + b * 197;
    float f = fr[idx];
    float acc = pb[0] * f + ct_acc[idx];
    float beta = pb[196];
    ct[idx] = beta * f + (1.0f - beta) * acc;
}

extern "C" void kernel_launch(void* const* d_in, const int* in_sizes, int n_in,
                              void* d_out, int out_size, void* d_ws, size_t ws_size,
                              hipStream_t stream)
{
    const float* xt         = (const float*)d_in[0];
    const float* state_h    = (const float*)d_in[1];
    const float* state_c    = (const float*)d_in[2];
    const float* fc_feats   = (const float*)d_in[3];
    const float* att_feats  = (const float*)d_in[4];
    const float* obj_feats  = (const float*)d_in[5];
    const float* attr_feats = (const float*)d_in[6];
    const float* rela_feats = (const float*)d_in[7];
    const float* p_obj      = (const float*)d_in[8];
    const float* p_attr     = (const float*)d_in[9];
    const float* p_rela     = (const float*)d_in[10];
    const float* att_masks  = (const float*)d_in[11];
    const float* rela_masks = (const float*)d_in[12];
    const float* att_wih    = (const float*)d_in[13];
    const float* att_whh    = (const float*)d_in[14];
    const float* att_bih    = (const float*)d_in[15];
    const float* att_bhh    = (const float*)d_in[16];
    const float* lang_wih   = (const float*)d_in[17];
    const float* lang_whh   = (const float*)d_in[18];
    const float* lang_bih   = (const float*)d_in[19];
    const float* lang_bhh   = (const float*)d_in[20];
    const float* xt2_w      = (const float*)d_in[21];
    const float* xt2_b      = (const float*)d_in[22];
    const float* h_att2_w   = (const float*)d_in[23];
    const float* h_att2_b   = (const float*)d_in[24];
    const float* r_i2h_w    = (const float*)d_in[25];
    const float* r_i2h_b    = (const float*)d_in[26];
    const float* r_h2h_w    = (const float*)d_in[27];
    const float* r_h2h_b    = (const float*)d_in[28];
    const float* huu_w      = (const float*)d_in[29];
    const float* huu_b      = (const float*)d_in[30];
    const float* obj_h2att_w  = (const float*)d_in[31];
    const float* obj_h2att_b  = (const float*)d_in[32];
    const float* obj_alpha_w  = (const float*)d_in[33];
    const float* attr_h2att_w = (const float*)d_in[35];
    const float* attr_h2att_b = (const float*)d_in[36];
    const float* attr_alpha_w = (const float*)d_in[37];
    const float* rela_h2att_w = (const float*)d_in[39];
    const float* rela_h2att_b = (const float*)d_in[40];
    const float* rela_alpha_w = (const float*)d_in[41];
    const float* fr_lin_w   = (const float*)d_in[43];
    const float* fr_lin_b   = (const float*)d_in[44];
    const float* fr_emb_w   = (const float*)d_in[45];
    const float* fr_emb_b   = (const float*)d_in[46];
    const float* ho_lin_w   = (const float*)d_in[47];
    const float* ho_lin_b   = (const float*)d_in[48];
    const float* ho_emb_w   = (const float*)d_in[49];
    const float* ho_emb_b   = (const float*)d_in[50];
    const float* ada_w      = (const float*)d_in[51];
    const float* cfe_w      = (const float*)d_in[53];
    const float* cfe_b      = (const float*)d_in[54];

    float* out = (float*)d_out;
    float* wsf = (float*)d_ws;

    // ---- ws layout (floats). [0, NATOM) = atomic targets, zeroed upfront.
    float* g        = wsf + 0;         // 128x4096
    float* lang_in  = wsf + 524288;    // 128x4096 [h_att|obj|attr|rela]
    float* att_h3   = wsf + 1048576;   // 3 x 128x512
    float* n5       = wsf + 1245184;   // 128x1024
    float* fr       = wsf + 1376256;   // 128x1024
    float* fre      = wsf + 1507328;   // 128x1024
    float* ho       = wsf + 1638400;   // 128x1024
    float* hoe      = wsf + 1769472;   // 128x1024
    float* e_ada    = wsf + 1900544;   // 128x197 (atomic, pad 25600)
    const int NATOM = 1926144;
    float* att_in    = wsf + 1926144;  // 128x3072 (dead after step 2)
    float* ct_acc    = att_in;         // alias: zeroed in relutanh
    float* h_att_raw = wsf + 2319360;  // 128x1024
    float* e3        = wsf + 2450432;  // 58368 (pad 76800)
    float* st        = wsf + 2527232;  // 128x1024
    float* ct        = wsf + 2658304;  // 128x1024
    short* Pbf       = (short*)(wsf + 2789376);   // 12845056 bf16, FRAGMENT order
    short* Wbf       = Pbf + 12845056;            // 524288 bf16, fragment order
    const bool big = ws_size >= (size_t)2789376 * 4 + (size_t)13369344 * 2;

    float* h_att_out  = out + 131072;
    float* h_lang_out = out + 262144;
    float* c_att_out  = out + 393216;
    float* c_lang_out = out + 524288;

    const float* prev_h = state_h + 131072;

    GJob Z = {};
    auto mk = [&](const float* A1, int lda1, int K1, const float* W1, int ldw1,
                  float* C, int ldc, int N, int Ktot, int Kchunk) {
        GJob j = Z;
        j.A1 = A1; j.lda1 = lda1; j.K1 = K1; j.K12 = Ktot; j.Ktot = Ktot;
        j.W1 = W1; j.ldw1 = ldw1;
        j.C = C; j.ldc = ldc; j.Kchunk = Kchunk; j.nb = N / 64;
        return j;
    };

    // 1. fused prologue: zero + out-bias + concat3 + fragment-order tobf16
    {
        const int ZB = (NATOM + 131072) / 256;          // 8036
        int grid = ZB + 384 + (big ? 6528 : 0);
        prologue_kernel<<<grid, 256, 0, stream>>>(wsf, NATOM, out, huu_b,
            prev_h, fc_feats, xt, att_in, p_obj, cfe_w, Pbf, Wbf, ZB);
    }

    // 2. att-LSTM gates  (SK=8)
    {
        GJob j = mk(att_in, 3072, 3072, att_wih, 3072, g, 4096, 4096, 4096, 512);
        j.A2 = state_h; j.lda2 = 1024; j.W2 = att_whh; j.ldw2 = 1024; j.K12 = 4096;
        gemm_sk_kernel<<<dim3(64, 8), 256, 0, stream>>>(j, Z, Z, 1);
    }
    // 3. att LSTM cell
    lstm_kernel<<<128, 256, 0, stream>>>(g, att_bih, att_bhh, state_c, h_att_raw, c_att_out,
                                         nullptr, nullptr, nullptr, nullptr);

    // 4. h_att -> lang_in col 0  (SK=16)
    {
        GJob j = mk(xt, 1024, 1024, xt2_w, 1024, lang_in, 4096, 1024, 2048, 128);
        j.A2 = h_att_raw; j.lda2 = 1024; j.W2 = h_att2_w; j.ldw2 = 1024; j.K12 = 2048;
        gemm_sk_kernel<<<dim3(16, 16), 256, 0, stream>>>(j, Z, Z, 1);
    }
    // 5. h_att bias + copy out
    hatt_epi_kernel<<<128, 256, 0, stream>>>(lang_in, xt2_b, h_att2_b, h_att_out);

    // 6. three h2att GEMMs in one launch (SK=16)
    {
        GJob j0 = mk(lang_in, 4096, 1024, obj_h2att_w,  1024, att_h3 + 0,      512, 512, 1024, 64);
        GJob j1 = mk(lang_in, 4096, 1024, attr_h2att_w, 1024, att_h3 + 65536,  512, 512, 1024, 64);
        GJob j2 = mk(lang_in, 4096, 1024, rela_h2att_w, 1024, att_h3 + 131072, 512, 512, 1024, 64);
        gemm_sk_kernel<<<dim3(24, 16), 256, 0, stream>>>(j0, j1, j2, 3);
    }
    // 7-9. fused e / softmax / wsum (s-split x4)
    att_e3_kernel<<<14592, 256, 0, stream>>>(p_obj, p_attr, p_rela, att_h3,
        obj_h2att_b, attr_h2att_b, rela_h2att_b, obj_alpha_w, attr_alpha_w, rela_alpha_w, e3);
    softmax3_kernel<<<384, 256, 0, stream>>>(e3, att_masks, rela_masks);
    wsum3_kernel<<<dim3(384, 4), 256, 0, stream>>>(e3, obj_feats, attr_feats, rela_feats, lang_in);

    // 10. lang gates + n5 (share A) in one launch (SK=8)
    {
        GJob j0 = mk(lang_in, 4096, 4096, lang_wih, 4096, g, 4096, 4096, 5120, 640);
        j0.A2 = prev_h; j0.lda2 = 1024; j0.W2 = lang_whh; j0.ldw2 = 1024; j0.K12 = 5120;
        GJob j1 = mk(lang_in, 4096, 4096, r_i2h_w, 4096, n5, 1024, 1024, 5120, 640);
        j1.A2 = prev_h; j1.lda2 = 1024; j1.W2 = r_h2h_w; j1.ldw2 = 1024; j1.K12 = 5120;
        gemm_sk_kernel<<<dim3(80, 8), 256, 0, stream>>>(j0, j1, Z, 2);
    }
    // 11. lang LSTM cell + st fused
    lstm_kernel<<<128, 256, 0, stream>>>(g, lang_bih, lang_bhh, state_c + 131072,
                                         h_lang_out, c_lang_out, n5, r_i2h_b, r_h2h_b, st);

    // 12. fr + ho GEMMs (SK=16)
    {
        GJob j0 = mk(st, 1024, 1024, fr_lin_w, 1024, fr, 1024, 1024, 1024, 64);
        GJob j1 = mk(h_lang_out, 1024, 1024, ho_lin_w, 1024, ho, 1024, 1024, 1024, 64);
        gemm_sk_kernel<<<dim3(32, 16), 256, 0, stream>>>(j0, j1, Z, 2);
    }
    // 13. relu/tanh epilogue + zero ct_acc
    relutanh_kernel<<<1024, 256, 0, stream>>>(fr, fr_lin_b, ho, ho_lin_b, ct_acc);

    // 14. fre + hoe GEMMs (SK=16; biases folded downstream)
    {
        GJob j0 = mk(fr, 1024, 1024, fr_emb_w, 1024, fre, 1024, 1024, 1024, 64);
        GJob j1 = mk(ho, 1024, 1024, ho_emb_w, 1024, hoe, 1024, 1024, 1024, 64);
        gemm_sk_kernel<<<dim3(32, 16), 256, 0, stream>>>(j0, j1, Z, 2);
    }
    // 15. cfe -> e_ada[1..196]
    if (big) {
        cfe_v7_kernel<<<1600, 256, 0, stream>>>(Pbf, Wbf, cfe_b, hoe, ho_emb_b, ada_w, e_ada);
    } else {
        cfe_fallback_kernel<<<1600, 256, 0, stream>>>(p_obj, cfe_w, cfe_b, hoe, ho_emb_b, ada_w, e_ada);
    }
    // 16. adaptive softmax (fused slot-0)
    softmax_ada_kernel<<<128, 256, 0, stream>>>(e_ada, fre, fr_emb_b, hoe, ho_emb_b, ada_w);
    // 17-18. c_t_hat
    ct_part_kernel<<<dim3(128, 14), 256, 0, stream>>>(e_ada, att_feats, ct_acc);
    ct_fin_kernel<<<512, 256, 0, stream>>>(e_ada, fr, ct_acc, ct);

    // 19. output = [h_att | h_lang | c_t_hat] @ huu^T (bias pre-initialized, SK=16)
    {
        GJob j = mk(lang_in, 4096, 1024, huu_w, 3072, out, 1024, 1024, 3072, 192);
        j.A2 = h_lang_out; j.lda2 = 1024; j.W2 = huu_w + 1024; j.ldw2 = 3072; j.K12 = 2048;
        j.A3 = ct; j.lda3 = 1024; j.W3 = huu_w + 2048; j.ldw3 = 3072;
        gemm_sk_kernel<<<dim3(16, 16), 256, 0, stream>>>(j, Z, Z, 1);
    }

    (void)in_sizes; (void)n_in; (void)out_size; (void)ws_size;
}

// Round 11
// 387.186 us; speedup vs baseline: 1.0891x; 1.0533x over previous
//
#include <hip/hip_runtime.h>
#include <cstddef>

#define B 128
#define R 1024

typedef __attribute__((ext_vector_type(8))) short short8;
typedef __attribute__((ext_vector_type(4))) float f32x4;

__device__ __forceinline__ float sigf(float x) { return 1.0f / (1.0f + __expf(-x)); }

__device__ __forceinline__ short f2bf(float f) {
    unsigned int u = __float_as_uint(f);
    u += 0x7fff + ((u >> 16) & 1);   // RNE
    return (short)(u >> 16);
}

__device__ __forceinline__ short8 cvt8(float4 u, float4 v) {
    short8 r;
    r[0] = f2bf(u.x); r[1] = f2bf(u.y); r[2] = f2bf(u.z); r[3] = f2bf(u.w);
    r[4] = f2bf(v.x); r[5] = f2bf(v.y); r[6] = f2bf(v.z); r[7] = f2bf(v.w);
    return r;
}

__device__ __forceinline__ void gll16(const void* g, void* l) {
    __builtin_amdgcn_global_load_lds(
        (const __attribute__((address_space(1))) unsigned int*)g,
        (__attribute__((address_space(3))) unsigned int*)l, 16, 0, 0);
}

// ---------------------------------------------------------------------------
// Split-K multi-job bf16-MFMA GEMM v2: double-buffered LDS, ONE barrier per
// BK=32 round; next round's global loads issued before MFMA (latency hidden).
// Optional A-activation during staging (aact: 1=relu(x+ab), 2=tanh(x+ab)).
// C[m,n] += sum_k A[m,k]*W[n,k] via atomicAdd (C pre-zeroed).
// ---------------------------------------------------------------------------
struct GJob {
    const float* A1; const float* A2; const float* A3;
    const float* W1; const float* W2; const float* W3;
    const float* abias;
    float* C;
    int lda1, lda2, lda3;
    int ldw1, ldw2, ldw3;
    int K1, K12, Ktot;
    int ldc, Kchunk, nb, aact;
};

__global__ __launch_bounds__(256) void gemm_sk_kernel(GJob j0, GJob j1, GJob j2, int njobs)
{
    GJob j = j0;
    int nbx = blockIdx.x;
    if (njobs > 1 && nbx >= j.nb) { nbx -= j.nb; j = j1; }
    if (njobs > 2 && nbx >= j.nb) { nbx -= j.nb; j = j2; }

    const int bn   = nbx * 64;
    const int kbeg = blockIdx.y * j.Kchunk;

    __shared__ short sA[2][128 * 40];
    __shared__ short sB[2][64 * 40];
    const int tid  = threadIdx.x;
    const int rA   = tid >> 1;
    const int kha  = (tid & 1) << 4;
    const int rB   = tid >> 2;
    const int khb  = (tid & 3) << 3;
    const int lane = tid & 63;
    const int wid  = tid >> 6;
    const int wm   = wid * 32;
    const int fr_  = lane & 15;
    const int kof  = (lane >> 4) * 8;

    float4 a0, a1, a2, a3, w0, w1;
    auto LOAD = [&](int k0) {
        int kgA = k0 + kha;
        const float* pa;
        if (kgA < j.K1)       pa = j.A1 + (size_t)rA * j.lda1 + kgA;
        else if (kgA < j.K12) pa = j.A2 + (size_t)rA * j.lda2 + (kgA - j.K1);
        else                  pa = j.A3 + (size_t)rA * j.lda3 + (kgA - j.K12);
        a0 = ((const float4*)pa)[0];
        a1 = ((const float4*)pa)[1];
        a2 = ((const float4*)pa)[2];
        a3 = ((const float4*)pa)[3];
        if (j.aact) {
            float4 b0 = *(const float4*)(j.abias + kgA);
            float4 b1 = *(const float4*)(j.abias + kgA + 4);
            float4 b2 = *(const float4*)(j.abias + kgA + 8);
            float4 b3 = *(const float4*)(j.abias + kgA + 12);
            a0.x += b0.x; a0.y += b0.y; a0.z += b0.z; a0.w += b0.w;
            a1.x += b1.x; a1.y += b1.y; a1.z += b1.z; a1.w += b1.w;
            a2.x += b2.x; a2.y += b2.y; a2.z += b2.z; a2.w += b2.w;
            a3.x += b3.x; a3.y += b3.y; a3.z += b3.z; a3.w += b3.w;
            if (j.aact == 1) {
                a0.x = fmaxf(a0.x, 0.f); a0.y = fmaxf(a0.y, 0.f); a0.z = fmaxf(a0.z, 0.f); a0.w = fmaxf(a0.w, 0.f);
                a1.x = fmaxf(a1.x, 0.f); a1.y = fmaxf(a1.y, 0.f); a1.z = fmaxf(a1.z, 0.f); a1.w = fmaxf(a1.w, 0.f);
                a2.x = fmaxf(a2.x, 0.f); a2.y = fmaxf(a2.y, 0.f); a2.z = fmaxf(a2.z, 0.f); a2.w = fmaxf(a2.w, 0.f);
                a3.x = fmaxf(a3.x, 0.f); a3.y = fmaxf(a3.y, 0.f); a3.z = fmaxf(a3.z, 0.f); a3.w = fmaxf(a3.w, 0.f);
            } else {
                a0.x = tanhf(a0.x); a0.y = tanhf(a0.y); a0.z = tanhf(a0.z); a0.w = tanhf(a0.w);
                a1.x = tanhf(a1.x); a1.y = tanhf(a1.y); a1.z = tanhf(a1.z); a1.w = tanhf(a1.w);
                a2.x = tanhf(a2.x); a2.y = tanhf(a2.y); a2.z = tanhf(a2.z); a2.w = tanhf(a2.w);
                a3.x = tanhf(a3.x); a3.y = tanhf(a3.y); a3.z = tanhf(a3.z); a3.w = tanhf(a3.w);
            }
        }
        int kgB = k0 + khb;
        const float* pw;
        if (kgB < j.K1)       pw = j.W1 + (size_t)(bn + rB) * j.ldw1 + kgB;
        else if (kgB < j.K12) pw = j.W2 + (size_t)(bn + rB) * j.ldw2 + (kgB - j.K1);
        else                  pw = j.W3 + (size_t)(bn + rB) * j.ldw3 + (kgB - j.K12);
        w0 = ((const float4*)pw)[0];
        w1 = ((const float4*)pw)[1];
    };
    auto WRITE = [&](int buf) {
        *(short8*)&sA[buf][rA * 40 + kha]     = cvt8(a0, a1);
        *(short8*)&sA[buf][rA * 40 + kha + 8] = cvt8(a2, a3);
        *(short8*)&sB[buf][rB * 40 + khb]     = cvt8(w0, w1);
    };

    f32x4 acc[2][4];
#pragma unroll
    for (int m = 0; m < 2; ++m)
#pragma unroll
        for (int n = 0; n < 4; ++n)
            acc[m][n] = (f32x4)0.0f;

    LOAD(kbeg);
    WRITE(0);
    __syncthreads();
    const int nr = j.Kchunk >> 5;
    for (int r = 0; r < nr; ++r) {
        const int buf = r & 1;
        const bool more = (r + 1 < nr);
        if (more) LOAD(kbeg + (r + 1) * 32);
        short8 af[2], bf[4];
#pragma unroll
        for (int m = 0; m < 2; ++m)
            af[m] = *(const short8*)&sA[buf][(wm + m * 16 + fr_) * 40 + kof];
#pragma unroll
        for (int n = 0; n < 4; ++n)
            bf[n] = *(const short8*)&sB[buf][(n * 16 + fr_) * 40 + kof];
#pragma unroll
        for (int m = 0; m < 2; ++m)
#pragma unroll
            for (int n = 0; n < 4; ++n)
                acc[m][n] = __builtin_amdgcn_mfma_f32_16x16x32_bf16(af[m], bf[n], acc[m][n], 0, 0, 0);
        if (more) WRITE(buf ^ 1);
        __syncthreads();
    }

#pragma unroll
    for (int m = 0; m < 2; ++m) {
        int row0 = wm + m * 16 + ((lane >> 4) << 2);
#pragma unroll
        for (int n = 0; n < 4; ++n) {
            int col = bn + n * 16 + fr_;
#pragma unroll
            for (int rg = 0; rg < 4; ++rg)
                atomicAdd(&j.C[(size_t)(row0 + rg) * j.ldc + col], acc[m][n][rg]);
        }
    }
}

// ---------------------------------------------------------------------------
// Fused prologue. Blocks:
//  [0,ZB): zero atomic ws (incl ct_acc) + init out bias
//  [ZB,ZB+384): concat3 -> att_in
//  [ZB+384, +6272): P -> Pbf in FRAGMENT order; then cfe_w -> Wbf
// ---------------------------------------------------------------------------
__global__ __launch_bounds__(256) void prologue_kernel(
    float* __restrict__ ws, int nws, float* __restrict__ o, const float* __restrict__ bias,
    const float* __restrict__ ph, const float* __restrict__ fc, const float* __restrict__ xt,
    float* __restrict__ att_in,
    const float* __restrict__ P, const float* __restrict__ W,
    short* __restrict__ Pbf, short* __restrict__ Wbf, int ZB)
{
    int blk = blockIdx.x;
    int tid = threadIdx.x;
    if (blk < ZB) {
        int idx = blk * 256 + tid;
        if (idx < nws) ws[idx] = 0.0f;
        else if (idx < nws + 131072) { int i = idx - nws; o[i] = bias[i & 1023]; }
        return;
    }
    blk -= ZB;
    if (blk < 384) {
        int idx = blk * 256 + tid;
        int r = idx / 768, c4 = idx - r * 768;
        int col = c4 * 4;
        const float* src = (col < 1024) ? (ph + (size_t)r * 1024 + col)
                         : (col < 2048) ? (fc + (size_t)r * 1024 + col - 1024)
                                        : (xt + (size_t)r * 1024 + col - 2048);
        *(float4*)(att_in + (size_t)r * 3072 + col) = *(const float4*)src;
        return;
    }
    blk -= 384;
    int lane = tid & 63;
    int fr = lane & 15, kg = lane >> 4;
    if (blk < 6272) {
        int w = blk * 4 + (tid >> 6);     // 0..25087 = rt*16+ks
        int rt = w >> 4, ks = w & 15;
        const float* src = P + (size_t)(rt * 16 + fr) * 512 + ks * 32 + kg * 8;
        float4 u = ((const float4*)src)[0];
        float4 v = ((const float4*)src)[1];
        *(short8*)(Pbf + ((size_t)w * 64 + lane) * 8) = cvt8(u, v);
    } else {
        int w = (blk - 6272) * 4 + (tid >> 6);   // 0..1023 = ct*16+ks
        int ct = w >> 4, ks = w & 15;
        const float* src = W + (size_t)(ct * 16 + fr) * 512 + ks * 32 + kg * 8;
        float4 u = ((const float4*)src)[0];
        float4 v = ((const float4*)src)[1];
        *(short8*)(Wbf + ((size_t)w * 64 + lane) * 8) = cvt8(u, v);
    }
}

// ---------------------------------------------------------------------------
// cfe v7b: m97 structure, fragment-ordered operands, gll16 staging,
// double-buffered, ONE barrier per round.
// ---------------------------------------------------------------------------
__global__ __launch_bounds__(256) void cfe_v7_kernel(
    const short* __restrict__ Pbf, const short* __restrict__ Wbf,
    const float* __restrict__ cb, const float* __restrict__ hoe,
    const float* __restrict__ ho_b, const float* __restrict__ aw,
    float* __restrict__ e)
{
    int p = blockIdx.x;
    int x8 = p & 7, rest = p >> 3;
    int n8 = rest & 7, q = rest >> 3;
    int m = q * 8 + x8;
    if (m >= 196) return;
    const int bm = m * 128, bn = n8 * 128;

    __shared__ short sA[2][8 * 512];
    __shared__ short sB[2][8 * 512];

    const int tid  = threadIdx.x;
    const int lane = tid & 63;
    const int wid  = tid >> 6;
    const int wm   = (wid >> 1) * 64;
    const int wn   = (wid & 1) * 64;
    const int fr_  = lane & 15;
    const int rtbA = bm >> 4;
    const int rtbB = bn >> 4;

    auto STAGE = [&](int buf, int ks) {
#pragma unroll
        for (int jj = 0; jj < 4; ++jj) {
            int fid = wid * 4 + jj;
            int rt  = fid & 7;
            if (fid < 8) {
                const short* src = Pbf + ((size_t)((rtbA + rt) * 16 + ks) * 64 + lane) * 8;
                gll16(src, &sA[buf][rt * 512]);
            } else {
                const short* src = Wbf + ((size_t)((rtbB + rt) * 16 + ks) * 64 + lane) * 8;
                gll16(src, &sB[buf][rt * 512]);
            }
        }
    };

    f32x4 acc[4][4];
#pragma unroll
    for (int mi = 0; mi < 4; ++mi)
#pragma unroll
        for (int n = 0; n < 4; ++n)
            acc[mi][n] = (f32x4)0.0f;

    STAGE(0, 0);
    for (int r = 0; r < 16; ++r) {
        const int buf = r & 1;
        __syncthreads();                       // staged buf ready; prior reads drained
        if (r < 15) STAGE(buf ^ 1, r + 1);     // prefetch next under compute
        short8 af[4], bf8[4];
#pragma unroll
        for (int mi = 0; mi < 4; ++mi)
            af[mi] = *(const short8*)&sA[buf][((wm >> 4) + mi) * 512 + lane * 8];
#pragma unroll
        for (int n = 0; n < 4; ++n)
            bf8[n] = *(const short8*)&sB[buf][((wn >> 4) + n) * 512 + lane * 8];
#pragma unroll
        for (int mi = 0; mi < 4; ++mi)
#pragma unroll
            for (int n = 0; n < 4; ++n)
                acc[mi][n] = __builtin_amdgcn_mfma_f32_16x16x32_bf16(af[mi], bf8[n], acc[mi][n], 0, 0, 0);
    }

    const int l4 = lane >> 4;
    const int rbase = bm + wm + (l4 << 2);
    const int b0 = rbase / 196;
    const int b1 = (rbase + 51) / 196;
    float cba[4], awa[4], hv0[4], hv1[4];
#pragma unroll
    for (int n = 0; n < 4; ++n) {
        int col = bn + wn + n * 16 + fr_;
        cba[n] = cb[col] + ho_b[col];
        awa[n] = aw[col];
        hv0[n] = hoe[(size_t)b0 * R + col];
        hv1[n] = hoe[(size_t)b1 * R + col];
    }
#pragma unroll
    for (int mi = 0; mi < 4; ++mi) {
#pragma unroll
        for (int rg = 0; rg < 4; ++rg) {
            int gr = rbase + mi * 16 + rg;
            int bb = gr / 196;
            bool second = (bb != b0);
            float part = 0.0f;
#pragma unroll
            for (int n = 0; n < 4; ++n) {
                float hv = second ? hv1[n] : hv0[n];
                part += tanhf(acc[mi][n][rg] + cba[n] + hv) * awa[n];
            }
            part += __shfl_xor(part, 1);
            part += __shfl_xor(part, 2);
            part += __shfl_xor(part, 4);
            part += __shfl_xor(part, 8);
            if (fr_ == 0)
                atomicAdd(&e[bb * 197 + 1 + (gr - bb * 196)], part);
        }
    }
}

// fallback (ws too small for Pbf): fp32 inputs + in-kernel cvt, LDS staged
__global__ __launch_bounds__(256) void cfe_fallback_kernel(
    const float* __restrict__ P, const float* __restrict__ Wf,
    const float* __restrict__ cb, const float* __restrict__ hoe,
    const float* __restrict__ ho_b, const float* __restrict__ aw,
    float* __restrict__ e)
{
    int p = blockIdx.x;
    int x8 = p & 7, rest = p >> 3;
    int n8 = rest & 7, q = rest >> 3;
    int m = q * 8 + x8;
    if (m >= 196) return;
    const int bm = m * 128, bn = n8 * 128;

    __shared__ short sA[128 * 72];
    __shared__ short sB[128 * 72];
    const int tid  = threadIdx.x;
    const int lane = tid & 63;
    const int wid  = tid >> 6;
    const int wm   = (wid >> 1) * 64;
    const int wn   = (wid & 1) * 64;
    const int fr_  = lane & 15;
    const int kof  = (lane >> 4) * 8;

    f32x4 acc[4][4];
#pragma unroll
    for (int mi = 0; mi < 4; ++mi)
#pragma unroll
        for (int n = 0; n < 4; ++n)
            acc[mi][n] = (f32x4)0.0f;

    for (int k0 = 0; k0 < 512; k0 += 64) {
        __syncthreads();
        int row = tid >> 1;
        int half = (tid & 1) * 32;
        const float* pa = P + (size_t)(bm + row) * 512 + k0 + half;
        const float* pw = Wf + (size_t)(bn + row) * 512 + k0 + half;
#pragma unroll
        for (int c = 0; c < 32; c += 8) {
            float4 u = *(const float4*)(pa + c);
            float4 v = *(const float4*)(pa + c + 4);
            *(short8*)&sA[row * 72 + half + c] = cvt8(u, v);
            float4 uw = *(const float4*)(pw + c);
            float4 vw = *(const float4*)(pw + c + 4);
            *(short8*)&sB[row * 72 + half + c] = cvt8(uw, vw);
        }
        __syncthreads();
#pragma unroll
        for (int ks = 0; ks < 64; ks += 32) {
            short8 af[4], bf[4];
#pragma unroll
            for (int mi = 0; mi < 4; ++mi)
                af[mi] = *(const short8*)&sA[(wm + mi * 16 + fr_) * 72 + ks + kof];
#pragma unroll
            for (int n = 0; n < 4; ++n)
                bf[n] = *(const short8*)&sB[(wn + n * 16 + fr_) * 72 + ks + kof];
#pragma unroll
            for (int mi = 0; mi < 4; ++mi)
#pragma unroll
                for (int n = 0; n < 4; ++n)
                    acc[mi][n] = __builtin_amdgcn_mfma_f32_16x16x32_bf16(af[mi], bf[n], acc[mi][n], 0, 0, 0);
        }
    }

    const int l4 = lane >> 4;
    const int rbase = bm + wm + (l4 << 2);
    const int b0 = rbase / 196;
    const int b1 = (rbase + 51) / 196;
    float cba[4], awa[4], hv0[4], hv1[4];
#pragma unroll
    for (int n = 0; n < 4; ++n) {
        int col = bn + wn + n * 16 + fr_;
        cba[n] = cb[col] + ho_b[col];
        awa[n] = aw[col];
        hv0[n] = hoe[(size_t)b0 * R + col];
        hv1[n] = hoe[(size_t)b1 * R + col];
    }
#pragma unroll
    for (int mi = 0; mi < 4; ++mi) {
#pragma unroll
        for (int rg = 0; rg < 4; ++rg) {
            int gr = rbase + mi * 16 + rg;
            int bb = gr / 196;
            bool second = (bb != b0);
            float part = 0.0f;
#pragma unroll
            for (int n = 0; n < 4; ++n) {
                float hv = second ? hv1[n] : hv0[n];
                part += tanhf(acc[mi][n][rg] + cba[n] + hv) * awa[n];
            }
            part += __shfl_xor(part, 1);
            part += __shfl_xor(part, 2);
            part += __shfl_xor(part, 4);
            part += __shfl_xor(part, 8);
            if (fr_ == 0)
                atomicAdd(&e[bb * 197 + 1 + (gr - bb * 196)], part);
        }
    }
}

// vectorized LSTM epilogue (+ optional st fusion); self-zero g.
__global__ __launch_bounds__(256) void lstm_kernel(
    float* __restrict__ g, const float* __restrict__ bih, const float* __restrict__ bhh,
    const float* __restrict__ cprev, float* __restrict__ h, float* __restrict__ c,
    const float* __restrict__ n5, const float* __restrict__ nb1,
    const float* __restrict__ nb2, float* __restrict__ st)
{
    int t = blockIdx.x * 256 + threadIdx.x;
    int b = t >> 8, d4 = (t & 255) * 4;
    float* gr = g + (size_t)b * 4096;
    float4 gi = *(float4*)(gr + d4);
    float4 gf = *(float4*)(gr + 1024 + d4);
    float4 gg = *(float4*)(gr + 2048 + d4);
    float4 go = *(float4*)(gr + 3072 + d4);
    float4 bi1 = *(const float4*)(bih + d4),        bh1 = *(const float4*)(bhh + d4);
    float4 bi2 = *(const float4*)(bih + 1024 + d4), bh2 = *(const float4*)(bhh + 1024 + d4);
    float4 bi3 = *(const float4*)(bih + 2048 + d4), bh3 = *(const float4*)(bhh + 2048 + d4);
    float4 bi4 = *(const float4*)(bih + 3072 + d4), bh4 = *(const float4*)(bhh + 3072 + d4);
    float4 cp = *(const float4*)(cprev + (size_t)b * 1024 + d4);
    float4 zero = {0.f, 0.f, 0.f, 0.f};
    *(float4*)(gr + d4) = zero; *(float4*)(gr + 1024 + d4) = zero;
    *(float4*)(gr + 2048 + d4) = zero; *(float4*)(gr + 3072 + d4) = zero;
    float4 cc, hh;
    float iv, fv, gv, ov, c2, tc;
    iv = sigf(gi.x + bi1.x + bh1.x); fv = sigf(gf.x + bi2.x + bh2.x);
    gv = tanhf(gg.x + bi3.x + bh3.x); ov = sigf(go.x + bi4.x + bh4.x);
    c2 = fv * cp.x + iv * gv; tc = tanhf(c2); cc.x = c2; hh.x = ov * tc;
    float tcx = tc;
    iv = sigf(gi.y + bi1.y + bh1.y); fv = sigf(gf.y + bi2.y + bh2.y);
    gv = tanhf(gg.y + bi3.y + bh3.y); ov = sigf(go.y + bi4.y + bh4.y);
    c2 = fv * cp.y + iv * gv; tc = tanhf(c2); cc.y = c2; hh.y = ov * tc;
    float tcy = tc;
    iv = sigf(gi.z + bi1.z + bh1.z); fv = sigf(gf.z + bi2.z + bh2.z);
    gv = tanhf(gg.z + bi3.z + bh3.z); ov = sigf(go.z + bi4.z + bh4.z);
    c2 = fv * cp.z + iv * gv; tc = tanhf(c2); cc.z = c2; hh.z = ov * tc;
    float tcz = tc;
    iv = sigf(gi.w + bi1.w + bh1.w); fv = sigf(gf.w + bi2.w + bh2.w);
    gv = tanhf(gg.w + bi3.w + bh3.w); ov = sigf(go.w + bi4.w + bh4.w);
    c2 = fv * cp.w + iv * gv; tc = tanhf(c2); cc.w = c2; hh.w = ov * tc;
    float tcw = tc;
    *(float4*)(c + (size_t)b * 1024 + d4) = cc;
    *(float4*)(h + (size_t)b * 1024 + d4) = hh;
    if (st) {
        float4 nv = *(const float4*)(n5 + (size_t)b * 1024 + d4);
        float4 n1 = *(const float4*)(nb1 + d4), n2 = *(const float4*)(nb2 + d4);
        float4 sv;
        sv.x = sigf(nv.x + n1.x + n2.x) * tcx;
        sv.y = sigf(nv.y + n1.y + n2.y) * tcy;
        sv.z = sigf(nv.z + n1.z + n2.z) * tcz;
        sv.w = sigf(nv.w + n1.w + n2.w) * tcw;
        *(float4*)(st + (size_t)b * 1024 + d4) = sv;
    }
}

// h_att epilogue: lang_in[:,0:1024] += biases (in place) and copy to h_att_out
__global__ __launch_bounds__(256) void hatt_epi_kernel(
    float* __restrict__ lang_in, const float* __restrict__ b1,
    const float* __restrict__ b2, float* __restrict__ h_att_out)
{
    int t = blockIdx.x * 256 + threadIdx.x;
    int r = t >> 8, c4 = (t & 255) * 4;
    float4 v = *(float4*)(lang_in + (size_t)r * 4096 + c4);
    float4 x1 = *(const float4*)(b1 + c4), x2 = *(const float4*)(b2 + c4);
    v.x += x1.x + x2.x; v.y += x1.y + x2.y; v.z += x1.z + x2.z; v.w += x1.w + x2.w;
    *(float4*)(lang_in + (size_t)r * 4096 + c4) = v;
    *(float4*)(h_att_out + (size_t)r * 1024 + c4) = v;
}

// fused 3-module e (float4, coalesced)
__global__ __launch_bounds__(256) void att_e3_kernel(
    const float* __restrict__ p0, const float* __restrict__ p1, const float* __restrict__ p2,
    const float* __restrict__ ah3,
    const float* __restrict__ b0, const float* __restrict__ b1, const float* __restrict__ b2,
    const float* __restrict__ aw0, const float* __restrict__ aw1, const float* __restrict__ aw2,
    float* __restrict__ e3)
{
    int wid = threadIdx.x >> 6, lane = threadIdx.x & 63;
    int idx = blockIdx.x * 4 + wid;
    const float* p; const float* bb; const float* aw; int S, loc, mod;
    if (idx < 25088)      { mod = 0; loc = idx;          p = p0; bb = b0; aw = aw0; S = 196; }
    else if (idx < 50176) { mod = 1; loc = idx - 25088;  p = p1; bb = b1; aw = aw1; S = 196; }
    else                  { mod = 2; loc = idx - 50176;  p = p2; bb = b2; aw = aw2; S = 64; }
    int b = loc / S;
    const float4* pr = (const float4*)(p + (size_t)loc * 512);
    const float4* ab = (const float4*)(ah3 + (size_t)mod * 65536 + (size_t)b * 512);
    const float4* bb4 = (const float4*)bb;
    const float4* aw4 = (const float4*)aw;
    float sum = 0.0f;
#pragma unroll
    for (int k = 0; k < 2; ++k) {
        int a = k * 64 + lane;
        float4 pv = pr[a], av = ab[a], bv = bb4[a], wv = aw4[a];
        sum += tanhf(pv.x + av.x + bv.x) * wv.x;
        sum += tanhf(pv.y + av.y + bv.y) * wv.y;
        sum += tanhf(pv.z + av.z + bv.z) * wv.z;
        sum += tanhf(pv.w + av.w + bv.w) * wv.w;
    }
#pragma unroll
    for (int off = 32; off; off >>= 1) sum += __shfl_down(sum, off);
    if (lane == 0) e3[idx] = sum;
}

// fused 3-module softmax (mask + renorm), in place on e3
__global__ __launch_bounds__(256) void softmax3_kernel(
    float* __restrict__ e3, const float* __restrict__ am, const float* __restrict__ rm)
{
    __shared__ float red[256];
    int mod = blockIdx.x >> 7, b = blockIdx.x & 127, tid = threadIdx.x;
    int S = (mod == 2) ? 64 : 196;
    float* e = e3 + ((mod == 0) ? 0 : (mod == 1) ? 25088 : 50176) + (size_t)b * S;
    const float* mask = ((mod == 2) ? rm : am) + (size_t)b * S;
    float v = (tid < S) ? e[tid] : -3.4e38f;
    red[tid] = v; __syncthreads();
    for (int s = 128; s; s >>= 1) { if (tid < s) red[tid] = fmaxf(red[tid], red[tid + s]); __syncthreads(); }
    float m = red[0]; __syncthreads();
    float p = (tid < S) ? __expf(v - m) : 0.0f;
    red[tid] = p; __syncthreads();
    for (int s = 128; s; s >>= 1) { if (tid < s) red[tid] += red[tid + s]; __syncthreads(); }
    float s1 = red[0]; __syncthreads();
    float w = (tid < S) ? (p / s1) * mask[tid] : 0.0f;
    red[tid] = w; __syncthreads();
    for (int s = 128; s; s >>= 1) { if (tid < s) red[tid] += red[tid + s]; __syncthreads(); }
    float s2 = red[0];
    if (tid < S) e[tid] = w / s2;
}

// fused 3-module weighted sum, s-split x4, atomic into lang_in (zeroed)
__global__ __launch_bounds__(256) void wsum3_kernel(
    const float* __restrict__ e3,
    const float* __restrict__ f0, const float* __restrict__ f1, const float* __restrict__ f2,
    float* __restrict__ lang_in)
{
    int mod = blockIdx.x >> 7;
    int idx = (blockIdx.x & 127) * 256 + threadIdx.x;
    int b = idx >> 8, d4 = idx & 255;
    int S = (mod == 2) ? 64 : 196;
    int Sq = (S + 3) >> 2;
    int s0 = blockIdx.y * Sq, s1 = min(S, s0 + Sq);
    const float4* f = (const float4*)(((mod == 0) ? f0 : (mod == 1) ? f1 : f2) + ((size_t)b * S) * R) + d4;
    const float* wb = e3 + ((mod == 0) ? 0 : (mod == 1) ? 25088 : 50176) + (size_t)b * S;
    float4 acc = {0.f, 0.f, 0.f, 0.f};
#pragma unroll 4
    for (int s = s0; s < s1; ++s) {
        float w = wb[s];
        float4 fv = f[(size_t)s * 256];
        acc.x = fmaf(w, fv.x, acc.x); acc.y = fmaf(w, fv.y, acc.y);
        acc.z = fmaf(w, fv.z, acc.z); acc.w = fmaf(w, fv.w, acc.w);
    }
    float* dst = lang_in + (size_t)b * 4096 + 1024 + mod * 1024 + d4 * 4;
    atomicAdd(dst + 0, acc.x); atomicAdd(dst + 1, acc.y);
    atomicAdd(dst + 2, acc.z); atomicAdd(dst + 3, acc.w);
}

// softmax over 197 with fused slot-0 compute
__global__ __launch_bounds__(256) void softmax_ada_kernel(
    float* __restrict__ e,
    const float* __restrict__ fre, const float* __restrict__ frb,
    const float* __restrict__ hoe, const float* __restrict__ hob,
    const float* __restrict__ aw)
{
    __shared__ float red[256];
    int b = blockIdx.x, tid = threadIdx.x;
    float s = 0.0f;
#pragma unroll
    for (int k = 0; k < 4; ++k) {
        int r = k * 256 + tid;
        s += tanhf(fre[(size_t)b * R + r] + frb[r] + hoe[(size_t)b * R + r] + hob[r]) * aw[r];
    }
    red[tid] = s; __syncthreads();
    for (int t = 128; t; t >>= 1) { if (tid < t) red[tid] += red[tid + t]; __syncthreads(); }
    float e0 = red[0]; __syncthreads();
    float v = (tid == 0) ? e0 : ((tid < 197) ? e[(size_t)b * 197 + tid] : -3.4e38f);
    red[tid] = v; __syncthreads();
    for (int t = 128; t; t >>= 1) { if (tid < t) red[tid] = fmaxf(red[tid], red[tid + t]); __syncthreads(); }
    float m = red[0]; __syncthreads();
    float p = (tid < 197) ? __expf(v - m) : 0.0f;
    red[tid] = p; __syncthreads();
    for (int t = 128; t; t >>= 1) { if (tid < t) red[tid] += red[tid + t]; __syncthreads(); }
    float s1 = red[0];
    if (tid < 197) e[(size_t)b * 197 + tid] = p / s1;
}

// c_t_hat partial: ct_acc += sum_{s in chunk of 14} PI[1+s]*attf  (atomic)
__global__ __launch_bounds__(256) void ct_part_kernel(
    const float* __restrict__ PI, const float* __restrict__ attf,
    float* __restrict__ ct_acc)
{
    int b = blockIdx.x, d4 = threadIdx.x;
    int s0 = blockIdx.y * 14, s1 = min(196, s0 + 14);
    const float* pb = PI + b * 197;
    const float4* af = (const float4*)(attf + ((size_t)b * 196) * R) + d4;
    float4 acc = {0.f, 0.f, 0.f, 0.f};
#pragma unroll 2
    for (int s = s0; s < s1; ++s) {
        float w = pb[1 + s];
        float4 av = af[(size_t)s * 256];
        acc.x = fmaf(w, av.x, acc.x); acc.y = fmaf(w, av.y, acc.y);
        acc.z = fmaf(w, av.z, acc.z); acc.w = fmaf(w, av.w, acc.w);
    }
    float* dst = ct_acc + (size_t)b * 1024 + d4 * 4;
    atomicAdd(dst + 0, acc.x); atomicAdd(dst + 1, acc.y);
    atomicAdd(dst + 2, acc.z); atomicAdd(dst + 3, acc.w);
}

// ct = beta*fr + (1-beta)*(PI[0]*fr + ct_acc), fr = relu(fr_raw + frb)
__global__ __launch_bounds__(256) void ct_fin_kernel(
    const float* __restrict__ PI, const float* __restrict__ fr_raw,
    const float* __restrict__ frb, const float* __restrict__ ct_acc,
    float* __restrict__ ct)
{
    int idx = blockIdx.x * 256 + threadIdx.x;
    int b = idx >> 10, c = idx & 1023;
    const float* pb = PI + b * 197;
    float f = fmaxf(fr_raw[idx] + frb[c], 0.0f);
    float acc = pb[0] * f + ct_acc[idx];
    float beta = pb[196];
    ct[idx] = beta * f + (1.0f - beta) * acc;
}

extern "C" void kernel_launch(void* const* d_in, const int* in_sizes, int n_in,
                              void* d_out, int out_size, void* d_ws, size_t ws_size,
                              hipStream_t stream)
{
    const float* xt         = (const float*)d_in[0];
    const float* state_h    = (const float*)d_in[1];
    const float* state_c    = (const float*)d_in[2];
    const float* fc_feats   = (const float*)d_in[3];
    const float* att_feats  = (const float*)d_in[4];
    const float* obj_feats  = (const float*)d_in[5];
    const float* attr_feats = (const float*)d_in[6];
    const float* rela_feats = (const float*)d_in[7];
    const float* p_obj      = (const float*)d_in[8];
    const float* p_attr     = (const float*)d_in[9];
    const float* p_rela     = (const float*)d_in[10];
    const float* att_masks  = (const float*)d_in[11];
    const float* rela_masks = (const float*)d_in[12];
    const float* att_wih    = (const float*)d_in[13];
    const float* att_whh    = (const float*)d_in[14];
    const float* att_bih    = (const float*)d_in[15];
    const float* att_bhh    = (const float*)d_in[16];
    const float* lang_wih   = (const float*)d_in[17];
    const float* lang_whh   = (const float*)d_in[18];
    const float* lang_bih   = (const float*)d_in[19];
    const float* lang_bhh   = (const float*)d_in[20];
    const float* xt2_w      = (const float*)d_in[21];
    const float* xt2_b      = (const float*)d_in[22];
    const float* h_att2_w   = (const float*)d_in[23];
    const float* h_att2_b   = (const float*)d_in[24];
    const float* r_i2h_w    = (const float*)d_in[25];
    const float* r_i2h_b    = (const float*)d_in[26];
    const float* r_h2h_w    = (const float*)d_in[27];
    const float* r_h2h_b    = (const float*)d_in[28];
    const float* huu_w      = (const float*)d_in[29];
    const float* huu_b      = (const float*)d_in[30];
    const float* obj_h2att_w  = (const float*)d_in[31];
    const float* obj_h2att_b  = (const float*)d_in[32];
    const float* obj_alpha_w  = (const float*)d_in[33];
    const float* attr_h2att_w = (const float*)d_in[35];
    const float* attr_h2att_b = (const float*)d_in[36];
    const float* attr_alpha_w = (const float*)d_in[37];
    const float* rela_h2att_w = (const float*)d_in[39];
    const float* rela_h2att_b = (const float*)d_in[40];
    const float* rela_alpha_w = (const float*)d_in[41];
    const float* fr_lin_w   = (const float*)d_in[43];
    const float* fr_lin_b   = (const float*)d_in[44];
    const float* fr_emb_w   = (const float*)d_in[45];
    const float* fr_emb_b   = (const float*)d_in[46];
    const float* ho_lin_w   = (const float*)d_in[47];
    const float* ho_lin_b   = (const float*)d_in[48];
    const float* ho_emb_w   = (const float*)d_in[49];
    const float* ho_emb_b   = (const float*)d_in[50];
    const float* ada_w      = (const float*)d_in[51];
    const float* cfe_w      = (const float*)d_in[53];
    const float* cfe_b      = (const float*)d_in[54];

    float* out = (float*)d_out;
    float* wsf = (float*)d_ws;

    // ---- ws layout (floats). [0, NATOM) = atomic targets, zeroed upfront.
    float* g        = wsf + 0;         // 128x4096
    float* lang_in  = wsf + 524288;    // 128x4096 [h_att|obj|attr|rela]
    float* att_h3   = wsf + 1048576;   // 3 x 128x512
    float* n5       = wsf + 1245184;   // 128x1024
    float* fr       = wsf + 1376256;   // 128x1024 (RAW; consumers apply relu+bias)
    float* fre      = wsf + 1507328;   // 128x1024
    float* ho       = wsf + 1638400;   // 128x1024 (RAW)
    float* hoe      = wsf + 1769472;   // 128x1024
    float* e_ada    = wsf + 1900544;   // 128x197 (pad 25600)
    float* ct_acc   = wsf + 1926144;   // 128x1024
    const int NATOM = 2057216;
    float* att_in    = wsf + 2057216;  // 128x3072
    float* h_att_raw = wsf + 2450432;  // 128x1024
    float* e3        = wsf + 2581504;  // 58368 (pad 76800)
    float* st        = wsf + 2658304;  // 128x1024
    float* ct        = wsf + 2789376;  // 128x1024
    short* Pbf       = (short*)(wsf + 2920448);   // 12845056 bf16, FRAGMENT order
    short* Wbf       = Pbf + 12845056;            // 524288 bf16
    const bool big = ws_size >= (size_t)2920448 * 4 + (size_t)13369344 * 2;

    float* h_att_out  = out + 131072;
    float* h_lang_out = out + 262144;
    float* c_att_out  = out + 393216;
    float* c_lang_out = out + 524288;

    const float* prev_h = state_h + 131072;

    GJob Z = {};
    auto mk = [&](const float* A1, int lda1, int K1, const float* W1, int ldw1,
                  float* C, int ldc, int N, int Ktot, int Kchunk) {
        GJob j = Z;
        j.A1 = A1; j.lda1 = lda1; j.K1 = K1; j.K12 = Ktot; j.Ktot = Ktot;
        j.W1 = W1; j.ldw1 = ldw1;
        j.C = C; j.ldc = ldc; j.Kchunk = Kchunk; j.nb = N / 64;
        return j;
    };

    // 1. fused prologue: zero (incl ct_acc) + out-bias + concat3 + tobf16
    {
        const int ZB = (NATOM + 131072) / 256;          // 8548
        int grid = ZB + 384 + (big ? 6528 : 0);
        prologue_kernel<<<grid, 256, 0, stream>>>(wsf, NATOM, out, huu_b,
            prev_h, fc_feats, xt, att_in, p_obj, cfe_w, Pbf, Wbf, ZB);
    }

    // 2. att-LSTM gates  (SK=8)
    {
        GJob j = mk(att_in, 3072, 3072, att_wih, 3072, g, 4096, 4096, 4096, 512);
        j.A2 = state_h; j.lda2 = 1024; j.W2 = att_whh; j.ldw2 = 1024; j.K12 = 4096;
        gemm_sk_kernel<<<dim3(64, 8), 256, 0, stream>>>(j, Z, Z, 1);
    }
    // 3. att LSTM cell
    lstm_kernel<<<128, 256, 0, stream>>>(g, att_bih, att_bhh, state_c, h_att_raw, c_att_out,
                                         nullptr, nullptr, nullptr, nullptr);

    // 4. h_att -> lang_in col 0  (SK=16)
    {
        GJob j = mk(xt, 1024, 1024, xt2_w, 1024, lang_in, 4096, 1024, 2048, 128);
        j.A2 = h_att_raw; j.lda2 = 1024; j.W2 = h_att2_w; j.ldw2 = 1024; j.K12 = 2048;
        gemm_sk_kernel<<<dim3(16, 16), 256, 0, stream>>>(j, Z, Z, 1);
    }
    // 5. h_att bias + copy out
    hatt_epi_kernel<<<128, 256, 0, stream>>>(lang_in, xt2_b, h_att2_b, h_att_out);

    // 6. three h2att GEMMs in one launch (SK=16)
    {
        GJob j0 = mk(lang_in, 4096, 1024, obj_h2att_w,  1024, att_h3 + 0,      512, 512, 1024, 64);
        GJob j1 = mk(lang_in, 4096, 1024, attr_h2att_w, 1024, att_h3 + 65536,  512, 512, 1024, 64);
        GJob j2 = mk(lang_in, 4096, 1024, rela_h2att_w, 1024, att_h3 + 131072, 512, 512, 1024, 64);
        gemm_sk_kernel<<<dim3(24, 16), 256, 0, stream>>>(j0, j1, j2, 3);
    }
    // 7-9. fused e / softmax / wsum (s-split x4)
    att_e3_kernel<<<14592, 256, 0, stream>>>(p_obj, p_attr, p_rela, att_h3,
        obj_h2att_b, attr_h2att_b, rela_h2att_b, obj_alpha_w, attr_alpha_w, rela_alpha_w, e3);
    softmax3_kernel<<<384, 256, 0, stream>>>(e3, att_masks, rela_masks);
    wsum3_kernel<<<dim3(384, 4), 256, 0, stream>>>(e3, obj_feats, attr_feats, rela_feats, lang_in);

    // 10. lang gates + n5 (share A) in one launch (SK=8)
    {
        GJob j0 = mk(lang_in, 4096, 4096, lang_wih, 4096, g, 4096, 4096, 5120, 640);
        j0.A2 = prev_h; j0.lda2 = 1024; j0.W2 = lang_whh; j0.ldw2 = 1024; j0.K12 = 5120;
        GJob j1 = mk(lang_in, 4096, 4096, r_i2h_w, 4096, n5, 1024, 1024, 5120, 640);
        j1.A2 = prev_h; j1.lda2 = 1024; j1.W2 = r_h2h_w; j1.ldw2 = 1024; j1.K12 = 5120;
        gemm_sk_kernel<<<dim3(80, 8), 256, 0, stream>>>(j0, j1, Z, 2);
    }
    // 11. lang LSTM cell + st fused
    lstm_kernel<<<128, 256, 0, stream>>>(g, lang_bih, lang_bhh, state_c + 131072,
                                         h_lang_out, c_lang_out, n5, r_i2h_b, r_h2h_b, st);

    // 12. fr + ho GEMMs (SK=16) -> raw outputs
    {
        GJob j0 = mk(st, 1024, 1024, fr_lin_w, 1024, fr, 1024, 1024, 1024, 64);
        GJob j1 = mk(h_lang_out, 1024, 1024, ho_lin_w, 1024, ho, 1024, 1024, 1024, 64);
        gemm_sk_kernel<<<dim3(32, 16), 256, 0, stream>>>(j0, j1, Z, 2);
    }
    // 13. fre + hoe GEMMs (SK=16); A-activation fused into staging
    {
        GJob j0 = mk(fr, 1024, 1024, fr_emb_w, 1024, fre, 1024, 1024, 1024, 64);
        j0.abias = fr_lin_b; j0.aact = 1;
        GJob j1 = mk(ho, 1024, 1024, ho_emb_w, 1024, hoe, 1024, 1024, 1024, 64);
        j1.abias = ho_lin_b; j1.aact = 2;
        gemm_sk_kernel<<<dim3(32, 16), 256, 0, stream>>>(j0, j1, Z, 2);
    }
    // 14. cfe -> e_ada[1..196]
    if (big) {
        cfe_v7_kernel<<<1600, 256, 0, stream>>>(Pbf, Wbf, cfe_b, hoe, ho_emb_b, ada_w, e_ada);
    } else {
        cfe_fallback_kernel<<<1600, 256, 0, stream>>>(p_obj, cfe_w, cfe_b, hoe, ho_emb_b, ada_w, e_ada);
    }
    // 15. adaptive softmax (fused slot-0)
    softmax_ada_kernel<<<128, 256, 0, stream>>>(e_ada, fre, fr_emb_b, hoe, ho_emb_b, ada_w);
    // 16-17. c_t_hat
    ct_part_kernel<<<dim3(128, 14), 256, 0, stream>>>(e_ada, att_feats, ct_acc);
    ct_fin_kernel<<<512, 256, 0, stream>>>(e_ada, fr, fr_lin_b, ct_acc, ct);

    // 18. output = [h_att | h_lang | c_t_hat] @ huu^T (bias pre-initialized, SK=16)
    {
        GJob j = mk(lang_in, 4096, 1024, huu_w, 3072, out, 1024, 1024, 3072, 192);
        j.A2 = h_lang_out; j.lda2 = 1024; j.W2 = huu_w + 1024; j.ldw2 = 3072; j.K12 = 2048;
        j.A3 = ct; j.lda3 = 1024; j.W3 = huu_w + 2048; j.ldw3 = 3072;
        gemm_sk_kernel<<<dim3(16, 16), 256, 0, stream>>>(j, Z, Z, 1);
    }

    (void)in_sizes; (void)n_in; (void)out_size; (void)ws_size;
}